// Round 16
// baseline (154.280 us; speedup 1.0000x reference)
//
#include <hip/hip_runtime.h>
#include <hip/hip_bf16.h>
#include <hip/hip_fp16.h>

#define EPSV 1e-5f
#define Bn 8
#define Cn 64
#define Hn 128
#define Wn 128
#define Pn (Hn*Wn)          // 16384
#define PR 150              // cdcm pad: 11 + 128 + 11
#define PE 130              // 1-pad: 1 + 128 + 1
#define YPAD_ELEMS (Bn*PR*PR*Cn)   // 11,520,000 fp16

typedef _Float16 v8h __attribute__((ext_vector_type(8)));
typedef float v16f __attribute__((ext_vector_type(16)));
typedef unsigned short ushort8v __attribute__((ext_vector_type(8)));
typedef unsigned short ushort4v __attribute__((ext_vector_type(4)));

__device__ __forceinline__ unsigned short f2h(float v) {
  _Float16 h = (_Float16)v;
  return *reinterpret_cast<const unsigned short*>(&h);
}
__device__ __forceinline__ float h2f(unsigned short u) {
  return (float)(*reinterpret_cast<const _Float16*>(&u));
}

__device__ __forceinline__ v8h exp8h(v8h x) {
  union { v8h v; __half2 h[4]; } u; u.v = x;
  #pragma unroll
  for (int i = 0; i < 4; i++) u.h[i] = h2exp(u.h[i]);
  return u.v;
}
__device__ __forceinline__ v8h rcp8h(v8h x) {
  union { v8h v; __half2 h[4]; } u; u.v = x;
  #pragma unroll
  for (int i = 0; i < 4; i++) u.h[i] = h2rcp(u.h[i]);
  return u.v;
}

// async global->LDS, 16B per lane; LDS dest = uniform base + lane*16
__device__ __forceinline__ void gload_lds16(const void* g, void* l) {
  __builtin_amdgcn_global_load_lds(
      (const __attribute__((address_space(1))) unsigned int*)g,
      (__attribute__((address_space(3))) unsigned int*)l, 16, 0, 0);
}

// channel-blocked CL addressing: [b][row][kb(4)][col][16], elems
__device__ __forceinline__ size_t clb(int b, int row, int kb, int col, int PD) {
  return ((((size_t)b * PD + row) * 4 + kb) * PD + col) * 16;
}

// batch-major XCD swizzle: 1024 blocks, XCD r gets batch r's rows in order
__device__ __forceinline__ void swz_bh(int& b, int& h) {
  int bid = blockIdx.x;
  int w = (bid & 7) * 128 + (bid >> 3);
  b = w >> 7; h = w & 127;
}

// ---------------- prep: weight packs + BN folds + border zeros --------------
// cdcm A-pack layout (18KB chunks): [d][kb][tap9][mh][512]
// other A-packs: [tap][kb][mh][lane*8+e], m=mh*32+(l&31), c=kb*16+(l>>5)*8+e
__global__ __launch_bounds__(256) void k_prep(
    const float* __restrict__ w1, const float* __restrict__ w5,
    const float* __restrict__ w7, const float* __restrict__ w9,
    const float* __restrict__ w11, const float* __restrict__ pww,
    const float* __restrict__ frw, const float* __restrict__ cw,
    const float* __restrict__ gww, const float* __restrict__ gwb,
    const float* __restrict__ gbg, const float* __restrict__ gbb,
    const float* __restrict__ gbm, const float* __restrict__ gbv,
    const float* __restrict__ ensw, const float* __restrict__ ensb,
    const float* __restrict__ bng, const float* __restrict__ bnb,
    const float* __restrict__ bnm, const float* __restrict__ bnv,
    const float* __restrict__ dww, const float* __restrict__ dwb,
    unsigned short* __restrict__ apack, unsigned short* __restrict__ apinv,
    unsigned short* __restrict__ apens, unsigned short* __restrict__ appw1,
    unsigned short* __restrict__ appw, unsigned short* __restrict__ apfr,
    unsigned short* __restrict__ gwpk,
    unsigned short* __restrict__ apk, unsigned short* __restrict__ bpk,
    unsigned short* __restrict__ dwpk, unsigned short* __restrict__ bdwpk,
    float* __restrict__ esc, float* __restrict__ ebi,
    unsigned short* __restrict__ ypad, unsigned short* __restrict__ spad)
{
  int id = blockIdx.x * 256 + threadIdx.x;
  if (id < 147456) {               // cdcm: chunked [d][kb][t9][mh][512]
    int c0 = id / 9216;            // ci = d*4 + kb
    int d = c0 >> 2, kb = c0 & 3;
    int r = id - c0 * 9216;
    int t9 = r / 1024;
    int r2 = r & 1023;
    int mh = r2 >> 9, l = (r2 >> 3) & 63, e = r2 & 7;
    int m = mh * 32 + (l & 31);
    int c = kb * 16 + (l >> 5) * 8 + e;
    const float* src = (d == 0) ? w5 : (d == 1) ? w7 : (d == 2) ? w9 : w11;
    apack[id] = f2h(src[(m * 64 + c) * 9 + t9]);
    return;
  }
  id -= 147456;
  if (id < 36864) {                // involution conv_w: 9 taps
    int e = id & 7, l = (id >> 3) & 63, mh = (id >> 9) & 1,
        kb = (id >> 10) & 3, tap = id >> 12;
    int m = mh * 32 + (l & 31);
    int c = kb * 16 + (l >> 5) * 8 + e;
    apinv[id] = f2h(cw[(m * 64 + c) * 9 + tap]);
    return;
  }
  id -= 36864;
  if (id < 36864) {                // ensemble mean weights: 9 taps
    int e = id & 7, l = (id >> 3) & 63, mh = (id >> 9) & 1,
        kb = (id >> 10) & 3, tap = id >> 12;
    int m = mh * 32 + (l & 31);
    int c = kb * 16 + (l >> 5) * 8 + e;
    float v = (ensw[((0 * 64 + m) * 64 + c) * 9 + tap] +
               ensw[((64 + m) * 64 + c) * 9 + tap] +
               ensw[((128 + m) * 64 + c) * 9 + tap]) * (1.f / 3.f);
    apens[id] = f2h(v);
    return;
  }
  id -= 36864;
  if (id < 4096) {                 // conv1 1x1
    int e = id & 7, l = (id >> 3) & 63, mh = (id >> 9) & 1, kb = (id >> 10) & 3;
    int m = mh * 32 + (l & 31);
    int c = kb * 16 + (l >> 5) * 8 + e;
    appw1[id] = f2h(w1[m * 64 + c]);
    return;
  }
  id -= 4096;
  if (id < 4096) {                 // dsc pointwise 1x1
    int e = id & 7, l = (id >> 3) & 63, mh = (id >> 9) & 1, kb = (id >> 10) & 3;
    int m = mh * 32 + (l & 31);
    int c = kb * 16 + (l >> 5) * 8 + e;
    appw[id] = f2h(pww[m * 64 + c]);
    return;
  }
  id -= 4096;
  if (id < 4096) {                 // fr 1x1
    int e = id & 7, l = (id >> 3) & 63, mh = (id >> 9) & 1, kb = (id >> 10) & 3;
    int m = mh * 32 + (l & 31);
    int c = kb * 16 + (l >> 5) * 8 + e;
    apfr[id] = f2h(frw[m * 64 + c]);
    return;
  }
  id -= 4096;
  if (id < 5184) {                 // packed gw weights [cblk8][tap81][ch8]
    int cblk = id / 648, r = id - cblk * 648;
    int tap = r >> 3, ch = r & 7;
    int c = cblk * 8 + ch;
    gwpk[id] = f2h(gww[c * 81 + tap]);
    return;
  }
  id -= 5184;
  if (id < 576) {                  // packed BN scale [cblk8][o9][ch8]
    int cblk = id / 72, r = id - cblk * 72;
    int o = r >> 3, ch = r & 7;
    int c = cblk * 8 + ch;
    float A = gbg[c * 9 + o] / sqrtf(gbv[c * 9 + o] + EPSV);
    apk[id] = f2h(A);
    return;
  }
  id -= 576;
  if (id < 576) {                  // packed BN shift
    int cblk = id / 72, r = id - cblk * 72;
    int o = r >> 3, ch = r & 7;
    int c = cblk * 8 + ch;
    float A = gbg[c * 9 + o] / sqrtf(gbv[c * 9 + o] + EPSV);
    float B = (gwb[c * 9 + o] - gbm[c * 9 + o]) * A + gbb[c * 9 + o];
    bpk[id] = f2h(B);
    return;
  }
  id -= 576;
  if (id < 576) {                  // packed depthwise weights [cblk8][tap9][ch8]
    int cblk = id / 72, r = id - cblk * 72;
    int tap = r >> 3, ch = r & 7;
    int c = cblk * 8 + ch;
    dwpk[id] = f2h(dww[c * 9 + tap]);
    return;
  }
  id -= 576;
  if (id < 64) {                   // packed 4*depthwise-bias [cblk8][ch8]
    bdwpk[id] = f2h(4.f * dwb[id]);
    return;
  }
  id -= 64;
  if (id < 64) {                   // final BN fold (+ mean ensemble bias)
    float s = bng[id] / sqrtf(bnv[id] + EPSV);
    esc[id] = s;
    float bm = (ensb[id] + ensb[64 + id] + ensb[128 + id]) * (1.f / 3.f);
    ebi[id] = (bm - bnm[id]) * s + bnb[id];
    return;
  }
  id -= 64;
  ushort8v z = {0, 0, 0, 0, 0, 0, 0, 0};
  const int perY = 22 * PR + 128 * 22;      // 6116: ypad border (pad 11)
  if (id < perY * Bn) {
    int b = id / perY; int r = id - b * perY;
    int tb = 22 * PR;
    int row, col;
    if (r < tb) {
      int rr = r / PR; col = r - rr * PR;
      row = (rr < 11) ? rr : (rr + 128);
    } else {
      int r2 = r - tb;
      row = 11 + r2 / 22;
      int cc = r2 % 22;
      col = (cc < 11) ? cc : (cc + 128);
    }
    #pragma unroll
    for (int kb = 0; kb < 4; kb++) {
      unsigned short* p = ypad + clb(b, row, kb, col, PR);
      *(ushort8v*)p = z;
      *(ushort8v*)(p + 8) = z;
    }
    return;
  }
  id -= perY * Bn;
  const int perS = 2 * PE + 256;            // 516: spad border (pad 1)
  if (id < perS * Bn) {
    int b = id / perS; int r = id - b * perS;
    int tb = 2 * PE;
    int row, col;
    if (r < tb) {
      int rr = r / PE; col = r - rr * PE;
      row = (rr < 1) ? 0 : 129;
    } else {
      int r2 = r - tb;
      row = 1 + r2 / 2;
      col = (r2 & 1) ? 129 : 0;
    }
    #pragma unroll
    for (int kb = 0; kb < 4; kb++) {
      unsigned short* p = spad + clb(b, row, kb, col, PE);
      *(ushort8v*)p = z;
      *(ushort8v*)(p + 8) = z;
    }
  }
}

// ---------------- stage 1: conv1x1(relu(x)) via MFMA, planar fp32 in --------
__global__ __launch_bounds__(256, 4) void k_pw1x(const float* __restrict__ x,
    const unsigned short* __restrict__ apw, const float* __restrict__ bias,
    unsigned short* __restrict__ ypad)
{
  int b, h; swz_bh(b, h);
  const int tid = threadIdx.x, wv = tid >> 6, l = tid & 63;
  const int ln31 = l & 31, g = l >> 5;
  const int px = wv * 32 + ln31;
  const float* xb = x + ((size_t)b * Cn) * Pn + h * Wn + px;
  v16f acc0, acc1;
  #pragma unroll
  for (int r = 0; r < 16; r++) { acc0[r] = 0.f; acc1[r] = 0.f; }
  const unsigned short* apl = apw + l * 8;
  #pragma unroll
  for (int kb = 0; kb < 4; kb++) {
    int c0 = kb * 16 + g * 8;
    v8h Bf;
    #pragma unroll
    for (int e = 0; e < 8; e++)
      Bf[e] = (_Float16)fmaxf(xb[(size_t)(c0 + e) * Pn], 0.f);
    v8h A0 = *(const v8h*)(apl + (kb * 2) * 512);
    v8h A1 = *(const v8h*)(apl + (kb * 2 + 1) * 512);
    acc0 = __builtin_amdgcn_mfma_f32_32x32x16_f16(A0, Bf, acc0, 0, 0, 0);
    acc1 = __builtin_amdgcn_mfma_f32_32x32x16_f16(A1, Bf, acc1, 0, 0, 0);
  }
  #pragma unroll
  for (int t = 0; t < 4; t++) {
    int c0 = 8 * t + 4 * g;
    int kb = c0 >> 4, sub = c0 & 15;
    ushort4v s0, s1;
    #pragma unroll
    for (int u = 0; u < 4; u++) {
      s0[u] = f2h(acc0[4 * t + u] + bias[c0 + u]);
      s1[u] = f2h(acc1[4 * t + u] + bias[c0 + u + 32]);
    }
    *(ushort4v*)(ypad + clb(b, h + 11, kb, px + 11, PR) + sub) = s0;
    *(ushort4v*)(ypad + clb(b, h + 11, kb + 2, px + 11, PR) + sub) = s1;
  }
}

// ---------------- stage 2: cdcm, persistent 16-wave block, pair phases ------
// grid 256, block 1024. 8 phases of (d, kb-pair) = 36 KB each, double
// buffered (72 KB LDS); A staged once per CU per phase (granules spread
// over waves: 0-3 take 3, rest 2); counted per-wave vmcnt, never 0
// mid-loop. 36 MFMA/wave per barrier pair hides staging + B latency.
__global__ __launch_bounds__(1024, 1) void k_cdcm_mfma(
    const unsigned short* __restrict__ ypad,
    const unsigned short* __restrict__ apack,
    unsigned short* __restrict__ spad)
{
  __shared__ __align__(16) unsigned short Abuf[2][18432];  // 2 x 36 KB
  const int bid = blockIdx.x;
  const int b = bid & 7, rg = bid >> 3;
  const int tid = threadIdx.x, wv = tid >> 6, l = tid & 63;
  const int ln31 = l & 31, g = l >> 5;
  const int h = rg * 4 + (wv >> 2);
  const int seg = (wv & 3) * 32;
  const int ng = (wv < 4) ? 3 : 2;   // granules this wave stages (36 total)

  // issue pair 0
  {
    const char* src = (const char*)apack;
    char* dst = (char*)&Abuf[0][0];
    for (int i = 0; i < ng; i++) {
      int off = (wv + i * 16) * 1024;
      gload_lds16(src + off + l * 16, dst + off);
    }
  }

  v16f acc0, acc1;
  #pragma unroll
  for (int r = 0; r < 16; r++) { acc0[r] = 0.f; acc1[r] = 0.f; }

  #pragma unroll
  for (int pp = 0; pp < 8; pp++) {
    const int d = pp >> 1, kbp = pp & 1;
    const int dil = 5 + 2 * d;
    if (pp < 7) {                  // prefetch next pair into other buffer
      const char* src = (const char*)(apack + (pp + 1) * 18432);
      char* dst = (char*)&Abuf[(pp + 1) & 1][0];
      for (int i = 0; i < ng; i++) {
        int off = (wv + i * 16) * 1024;
        gload_lds16(src + off + l * 16, dst + off);
      }
      if (wv < 4) asm volatile("s_waitcnt vmcnt(3)" ::: "memory");
      else        asm volatile("s_waitcnt vmcnt(2)" ::: "memory");
    } else {
      asm volatile("s_waitcnt vmcnt(0)" ::: "memory");
    }
    asm volatile("s_barrier" ::: "memory");

    __builtin_amdgcn_s_setprio(1);
    const unsigned short* abl = &Abuf[pp & 1][0] + l * 8;
    #pragma unroll
    for (int kbl = 0; kbl < 2; kbl++) {
      const int kb = kbp * 2 + kbl;
      #pragma unroll
      for (int ky = 0; ky < 3; ky++) {
        const int row = h + 11 + (ky - 1) * dil;
        #pragma unroll
        for (int kx = 0; kx < 3; kx++) {
          const int col = seg + ln31 + (kx - 1) * dil + 11;
          const int t9 = ky * 3 + kx;
          v8h Bf = *(const v8h*)(ypad + clb(b, row, kb, col, PR) + g * 8);
          const unsigned short* ap = abl + kbl * 9216 + t9 * 1024;
          v8h A0 = *(const v8h*)(ap);
          v8h A1 = *(const v8h*)(ap + 512);
          acc0 = __builtin_amdgcn_mfma_f32_32x32x16_f16(A0, Bf, acc0, 0, 0, 0);
          acc1 = __builtin_amdgcn_mfma_f32_32x32x16_f16(A1, Bf, acc1, 0, 0, 0);
        }
      }
    }
    __builtin_amdgcn_s_setprio(0);
    asm volatile("s_barrier" ::: "memory");  // waves done with buf[pp&1]
  }
  const int px = seg + ln31;
  #pragma unroll
  for (int t = 0; t < 4; t++) {
    int c0 = 8 * t + 4 * g;
    int kb = c0 >> 4, sub = c0 & 15;
    ushort4v s0, s1;
    #pragma unroll
    for (int u = 0; u < 4; u++) {
      s0[u] = f2h(acc0[4 * t + u]);
      s1[u] = f2h(acc1[4 * t + u]);
    }
    *(ushort4v*)(spad + clb(b, h + 1, kb, px + 1, PE) + sub) = s0;
    *(ushort4v*)(spad + clb(b, h + 1, kb + 2, px + 1, PE) + sub) = s1;
  }
}

// ---------------- stage 3: packed-fp16 depthwise + pointwise (MFMA) ---------
// Blocks h==0/h==1 also zero y2pad's pad-1 borders (safe: nothing reads
// y2pad until invol; border writes disjoint from all interior writes).
__global__ __launch_bounds__(256, 4) void k_dwpw_mfma(
    const unsigned short* __restrict__ spad,
    const unsigned short* __restrict__ dwpk,
    const unsigned short* __restrict__ bdwpk,
    const unsigned short* __restrict__ appw, const float* __restrict__ pwb,
    unsigned short* __restrict__ y2pad)
{
  const int tid = threadIdx.x;
  int b, h; swz_bh(b, h);

  ushort8v z = {0, 0, 0, 0, 0, 0, 0, 0};
  if (h == 0) {
    for (int px = tid; px < 260; px += 256) {
      int row = (px < 130) ? 0 : 129;
      int col = (px < 130) ? px : px - 130;
      #pragma unroll
      for (int kb = 0; kb < 4; kb++) {
        unsigned short* p = y2pad + clb(b, row, kb, col, PE);
        *(ushort8v*)p = z;
        *(ushort8v*)(p + 8) = z;
      }
    }
  } else if (h == 1) {
    int row = 1 + (tid & 127);
    int col = (tid >> 7) ? 129 : 0;
    #pragma unroll
    for (int kb = 0; kb < 4; kb++) {
      unsigned short* p = y2pad + clb(b, row, kb, col, PE);
      *(ushort8v*)p = z;
      *(ushort8v*)(p + 8) = z;
    }
  }

  const int wv = tid >> 6, l = tid & 63;
  const int ln31 = l & 31, g = l >> 5;
  const int w = wv * 32 + ln31;

  v16f acc0, acc1;
  #pragma unroll
  for (int r = 0; r < 16; r++) { acc0[r] = 0.f; acc1[r] = 0.f; }
  const unsigned short* apl = appw + l * 8;

  #pragma unroll
  for (int kb = 0; kb < 4; kb++) {
    const int cblk = kb * 2 + g;
    const unsigned short* wp = dwpk + cblk * 72;   // [tap9][ch8]
    v8h t[9];
    #pragma unroll
    for (int k = 0; k < 9; k++) {
      const int dy = k / 3 - 1, dx = k % 3 - 1;
      t[k] = *(const v8h*)(spad + clb(b, h + 1 + dy, kb, w + 1 + dx, PE) + g * 8);
    }
    v8h dv = *(const v8h*)(bdwpk + cblk * 8);      // 4*dw_bias packed
    #pragma unroll
    for (int k = 0; k < 9; k++)
      dv += (*(const v8h*)(wp + k * 8)) * t[k];
    v8h A0 = *(const v8h*)(apl + (kb * 2) * 512);
    v8h A1 = *(const v8h*)(apl + (kb * 2 + 1) * 512);
    acc0 = __builtin_amdgcn_mfma_f32_32x32x16_f16(A0, dv, acc0, 0, 0, 0);
    acc1 = __builtin_amdgcn_mfma_f32_32x32x16_f16(A1, dv, acc1, 0, 0, 0);
  }
  #pragma unroll
  for (int t = 0; t < 4; t++) {
    int c0 = 8 * t + 4 * g;
    int kb = c0 >> 4, sub = c0 & 15;
    ushort4v s0, s1;
    #pragma unroll
    for (int u = 0; u < 4; u++) {
      s0[u] = f2h(acc0[4 * t + u] + 4.f * pwb[c0 + u]);
      s1[u] = f2h(acc1[4 * t + u] + 4.f * pwb[c0 + u + 32]);
    }
    *(ushort4v*)(y2pad + clb(b, h + 1, kb, w + 1, PE) + sub) = s0;
    *(ushort4v*)(y2pad + clb(b, h + 1, kb + 2, w + 1, PE) + sub) = s1;
  }
}

// ---------------- stage 4: involution, packed-fp16 softmax + MFMA -----------
__global__ __launch_bounds__(256, 3) void k_invol_mfma(
    const unsigned short* __restrict__ y2pad,
    const unsigned short* __restrict__ gwpk,
    const unsigned short* __restrict__ apk,
    const unsigned short* __restrict__ bpk,
    const unsigned short* __restrict__ apinv,
    const float* __restrict__ cbias,
    unsigned short* __restrict__ ipad)
{
  __shared__ __align__(16) unsigned short gws[5184];  // [cblk8][tap81][ch8]
  __shared__ __align__(16) unsigned short As[576];    // [cblk8][o9][ch8]
  __shared__ __align__(16) unsigned short Bs[576];
  const int tid = threadIdx.x;
  for (int t = tid; t < 648; t += 256)
    ((ushort8v*)gws)[t] = ((const ushort8v*)gwpk)[t];
  if (tid < 72) {
    ((ushort8v*)As)[tid] = ((const ushort8v*)apk)[tid];
    ((ushort8v*)Bs)[tid] = ((const ushort8v*)bpk)[tid];
  }
  __syncthreads();

  int b, h; swz_bh(b, h);
  const int wv = tid >> 6, l = tid & 63;
  const int p32 = l & 31, g = l >> 5;
  const int w = wv * 32 + p32;

  v16f acc0, acc1;
  #pragma unroll
  for (int r = 0; r < 16; r++) { acc0[r] = 0.f; acc1[r] = 0.f; }

  for (int cb4 = 0; cb4 < 4; cb4++) {
    const int cblk = cb4 * 2 + g;
    const unsigned short* gwp = gws + cblk * 648;
    const unsigned short* Ap = As + cblk * 72;
    const unsigned short* Bp = Bs + cblk * 72;

    v8h pt[9];
    #pragma unroll
    for (int k = 0; k < 9; k++) {
      const int dy = k / 3 - 1, dx = k % 3 - 1;
      pt[k] = *(const v8h*)(y2pad + clb(b, h + 1 + dy, cb4, w + 1 + dx, PE) + g * 8);
    }
    // gw matmul + BN, all packed fp16 (weights broadcast from LDS)
    v8h s[9];
    #pragma unroll
    for (int o = 0; o < 9; o++) {
      v8h a = (*(const v8h*)(gwp + o * 72)) * pt[0];
      #pragma unroll
      for (int i = 1; i < 9; i++)
        a += (*(const v8h*)(gwp + o * 72 + i * 8)) * pt[i];
      s[o] = a * (*(const v8h*)(Ap + o * 8)) + (*(const v8h*)(Bp + o * 8));
    }
    // softmax over the 9 taps (shift-free: |s| << 1, fp16-safe)
    v8h esum = {0, 0, 0, 0, 0, 0, 0, 0};
    #pragma unroll
    for (int o = 0; o < 9; o++) { s[o] = exp8h(s[o]); esum += s[o]; }
    v8h inv = rcp8h(esum);
    #pragma unroll
    for (int k = 0; k < 9; k++) pt[k] = pt[k] * s[k] * inv;

    const unsigned short* ap = apinv + l * 8;
    __builtin_amdgcn_s_setprio(1);
    #pragma unroll
    for (int k = 0; k < 9; k++) {
      const unsigned short* a2 = ap + ((k * 4 + cb4) * 2) * 512;
      v8h A0 = *(const v8h*)(a2);
      v8h A1 = *(const v8h*)(a2 + 512);
      acc0 = __builtin_amdgcn_mfma_f32_32x32x16_f16(A0, pt[k], acc0, 0, 0, 0);
      acc1 = __builtin_amdgcn_mfma_f32_32x32x16_f16(A1, pt[k], acc1, 0, 0, 0);
    }
    __builtin_amdgcn_s_setprio(0);
  }
  #pragma unroll
  for (int t = 0; t < 4; t++) {
    int c0 = 8 * t + 4 * g;
    int kb = c0 >> 4, sub = c0 & 15;
    ushort4v s0, s1;
    #pragma unroll
    for (int u = 0; u < 4; u++) {
      s0[u] = f2h(acc0[4 * t + u] + cbias[c0 + u]);
      s1[u] = f2h(acc1[4 * t + u] + cbias[c0 + u + 32]);
    }
    *(ushort4v*)(ipad + clb(b, h, kb, w, 128) + sub) = s0;
    *(ushort4v*)(ipad + clb(b, h, kb + 2, w, 128) + sub) = s1;
  }
}

// ---------------- stage 5: fr 1x1 + residual (direct epilogue add) ----------
__global__ __launch_bounds__(256, 4) void k_fr_mfma(
    const unsigned short* __restrict__ ipad,
    const unsigned short* __restrict__ apfr,
    const float* __restrict__ bias,
    unsigned short* __restrict__ opad)
{
  int b, h; swz_bh(b, h);
  const int tid = threadIdx.x, wv = tid >> 6, l = tid & 63;
  const int ln31 = l & 31, g = l >> 5;
  const int px = wv * 32 + ln31;
  v16f acc0, acc1;
  #pragma unroll
  for (int r = 0; r < 16; r++) { acc0[r] = 0.f; acc1[r] = 0.f; }
  const unsigned short* apl = apfr + l * 8;
  #pragma unroll
  for (int kb = 0; kb < 4; kb++) {
    v8h Bf = *(const v8h*)(ipad + clb(b, h, kb, px, 128) + g * 8);
    v8h A0 = *(const v8h*)(apl + (kb * 2) * 512);
    v8h A1 = *(const v8h*)(apl + (kb * 2 + 1) * 512);
    acc0 = __builtin_amdgcn_mfma_f32_32x32x16_f16(A0, Bf, acc0, 0, 0, 0);
    acc1 = __builtin_amdgcn_mfma_f32_32x32x16_f16(A1, Bf, acc1, 0, 0, 0);
  }
  #pragma unroll
  for (int t = 0; t < 4; t++) {
    int c0 = 8 * t + 4 * g;
    int kb = c0 >> 4, sub = c0 & 15;
    // residual values live at exactly the epilogue addresses
    ushort4v r0 = *(const ushort4v*)(ipad + clb(b, h, kb, px, 128) + sub);
    ushort4v r1 = *(const ushort4v*)(ipad + clb(b, h, kb + 2, px, 128) + sub);
    ushort4v s0, s1;
    #pragma unroll
    for (int u = 0; u < 4; u++) {
      s0[u] = f2h(acc0[4 * t + u] + bias[c0 + u] + h2f(r0[u]));
      s1[u] = f2h(acc1[4 * t + u] + bias[c0 + u + 32] + h2f(r1[u]));
    }
    *(ushort4v*)(opad + clb(b, h + 1, kb, px + 1, PE) + sub) = s0;
    *(ushort4v*)(opad + clb(b, h + 1, kb + 2, px + 1, PE) + sub) = s1;
  }
}

// ---------------- stage 6: ensemble conv3x3, 2 rows/block, LDS weights ------
__global__ __launch_bounds__(256) void k_ens_mfma(
    const unsigned short* __restrict__ opad,
    const unsigned short* __restrict__ apens,
    const float* __restrict__ esc, const float* __restrict__ ebi,
    float* __restrict__ out)
{
  __shared__ __align__(16) unsigned short Abuf[36864];  // 72 KB: 9 taps
  const int tid = threadIdx.x;
  {
    const ushort8v* src = (const ushort8v*)apens;
    ushort8v* dst = (ushort8v*)Abuf;
    #pragma unroll
    for (int it = 0; it < 18; it++)
      dst[tid + it * 256] = src[tid + it * 256];
  }
  __syncthreads();

  const int bid = blockIdx.x;
  const int b = bid & 7, h0 = (bid >> 3) * 2;
  const int wv = tid >> 6, l = tid & 63;
  const int ln31 = l & 31, g = l >> 5;

  v16f a00, a01, a10, a11;
  #pragma unroll
  for (int r = 0; r < 16; r++) { a00[r] = 0.f; a01[r] = 0.f; a10[r] = 0.f; a11[r] = 0.f; }

  const unsigned short* abl = Abuf + l * 8;

  #pragma unroll
  for (int ky = 0; ky < 3; ky++) {
    #pragma unroll
    for (int kx = 0; kx < 3; kx++) {
      const int tap = ky * 3 + kx;
      const int r0 = h0 + ky;              // (h0+1) + (ky-1)
      const int col = wv * 32 + ln31 + kx; // (+1) + (kx-1)
      const unsigned short* ap = abl + tap * 4096;
      #pragma unroll
      for (int kb = 0; kb < 4; kb++) {
        v8h B0 = *(const v8h*)(opad + clb(b, r0, kb, col, PE) + g * 8);
        v8h B1 = *(const v8h*)(opad + clb(b, r0 + 1, kb, col, PE) + g * 8);
        v8h A0 = *(const v8h*)(ap + kb * 1024);
        v8h A1 = *(const v8h*)(ap + kb * 1024 + 512);
        a00 = __builtin_amdgcn_mfma_f32_32x32x16_f16(A0, B0, a00, 0, 0, 0);
        a01 = __builtin_amdgcn_mfma_f32_32x32x16_f16(A1, B0, a01, 0, 0, 0);
        a10 = __builtin_amdgcn_mfma_f32_32x32x16_f16(A0, B1, a10, 0, 0, 0);
        a11 = __builtin_amdgcn_mfma_f32_32x32x16_f16(A1, B1, a11, 0, 0, 0);
      }
    }
  }
  float* sp0 = out + ((size_t)b * Cn) * Pn + h0 * Wn + wv * 32 + ln31;
  float* sp1 = sp0 + Wn;
  #pragma unroll
  for (int r = 0; r < 16; r++) {
    int o0 = (r & 3) + 8 * (r >> 2) + 4 * g;
    float e0 = esc[o0], e1 = esc[o0 + 32];
    float i0 = ebi[o0], i1 = ebi[o0 + 32];
    sp0[(size_t)o0 * Pn] = fmaxf(a00[r] * e0 + i0, 0.f);
    sp0[(size_t)(o0 + 32) * Pn] = fmaxf(a01[r] * e1 + i1, 0.f);
    sp1[(size_t)o0 * Pn] = fmaxf(a10[r] * e0 + i0, 0.f);
    sp1[(size_t)(o0 + 32) * Pn] = fmaxf(a11[r] * e1 + i1, 0.f);
  }
}

extern "C" void kernel_launch(void* const* d_in, const int* in_sizes, int n_in,
                              void* d_out, int out_size, void* d_ws, size_t ws_size,
                              hipStream_t stream)
{
  const float* x    = (const float*)d_in[0];
  const float* w1   = (const float*)d_in[1];
  const float* b1   = (const float*)d_in[2];
  const float* w5   = (const float*)d_in[3];
  const float* w7   = (const float*)d_in[4];
  const float* w9   = (const float*)d_in[5];
  const float* w11  = (const float*)d_in[6];
  const float* dww  = (const float*)d_in[7];
  const float* dwb  = (const float*)d_in[8];
  const float* pww  = (const float*)d_in[9];
  const float* pwb  = (const float*)d_in[10];
  const float* gww  = (const float*)d_in[11];
  const float* gwb  = (const float*)d_in[12];
  const float* gbg  = (const float*)d_in[13];
  const float* gbb  = (const float*)d_in[14];
  const float* gbm  = (const float*)d_in[15];
  const float* gbv  = (const float*)d_in[16];
  const float* cw   = (const float*)d_in[17];
  const float* cb   = (const float*)d_in[18];
  const float* frw  = (const float*)d_in[19];
  const float* frb  = (const float*)d_in[20];
  const float* ensw = (const float*)d_in[21];
  const float* ensb = (const float*)d_in[22];
  const float* bng  = (const float*)d_in[23];
  const float* bnb  = (const float*)d_in[24];
  const float* bnm  = (const float*)d_in[25];
  const float* bnv  = (const float*)d_in[26];

  // ws: ypad (pad-11) region, overlaid later by y2pad then opad (pad-1)
  unsigned short* wsu   = (unsigned short*)d_ws;
  unsigned short* ypad  = wsu;
  unsigned short* y2pad = wsu;
  unsigned short* opad  = wsu;
  unsigned short* apack = wsu + YPAD_ELEMS;         // 147456
  unsigned short* apinv = apack + 147456;           // 36864
  unsigned short* apens = apinv + 36864;            // 36864
  unsigned short* appw1 = apens + 36864;            // 4096
  unsigned short* appw  = appw1 + 4096;             // 4096
  unsigned short* apfr  = appw + 4096;              // 4096
  unsigned short* gwpk  = apfr + 4096;              // 5184
  unsigned short* apk   = gwpk + 5184;              // 576
  unsigned short* bpk   = apk + 576;                // 576
  unsigned short* dwpk  = bpk + 576;                // 576
  unsigned short* bdwpk = dwpk + 576;               // 64
  float* esc = (float*)(bdwpk + 64);                // 64
  float* ebi = esc + 64;                            // 64

  // d_out: spad (fp16 blocked-CL pad-1) -> ipad (blocked-CL) -> planar fp32
  unsigned short* spad = (unsigned short*)d_out;
  unsigned short* ipad = (unsigned short*)d_out;
  float* D = (float*)d_out;

  // prep also zeroes ypad borders (pad 11) and spad borders (pad 1)
  k_prep<<<1147, 256, 0, stream>>>(w1, w5, w7, w9, w11, pww, frw, cw,
                                   gww, gwb, gbg, gbb, gbm, gbv, ensw, ensb,
                                   bng, bnb, bnm, bnv, dww, dwb,
                                   apack, apinv, apens, appw1, appw, apfr,
                                   gwpk, apk, bpk, dwpk, bdwpk, esc, ebi,
                                   ypad, spad);

  // 1) ypad = conv1x1(relu(x))           x (planar f32) -> ypad (blocked CL)
  k_pw1x<<<1024, 256, 0, stream>>>(x, appw1, b1, ypad);
  // 2) spad = sum_d dilconv_d(y)         ypad -> spad (d_out, pad-1)
  k_cdcm_mfma<<<256, 1024, 0, stream>>>(ypad, apack, spad);
  // 3) y2pad = PW(DW(spad))              spad -> y2pad (ws, pad-1)
  //    (blocks h=0/1 also zero y2pad borders; ypad is dead by now)
  k_dwpw_mfma<<<1024, 256, 0, stream>>>(spad, dwpk, bdwpk, appw, pwb, y2pad);
  // 4) ipad = involution(y2pad)          y2pad -> ipad (d_out)
  k_invol_mfma<<<1024, 256, 0, stream>>>(y2pad, gwpk, apk, bpk, apinv, cb, ipad);
  // 5) opad = fr(ipad) + ipad            ipad -> opad (ws, pad-1)
  k_fr_mfma<<<1024, 256, 0, stream>>>(ipad, apfr, frb, opad);
  // 6) out = relu(BN(ens3x3(opad)))      opad -> D (planar fp32)
  k_ens_mfma<<<512, 256, 0, stream>>>(opad, apens, esc, ebi, D);
}

// Round 17
// 152.872 us; speedup vs baseline: 1.0092x; 1.0092x over previous
//
#include <hip/hip_runtime.h>
#include <hip/hip_bf16.h>
#include <hip/hip_fp16.h>

#define EPSV 1e-5f
#define Bn 8
#define Cn 64
#define Hn 128
#define Wn 128
#define Pn (Hn*Wn)          // 16384
#define PR 150              // cdcm pad: 11 + 128 + 11
#define PE 130              // 1-pad: 1 + 128 + 1
#define YPAD_ELEMS (Bn*PR*PR*Cn)   // 11,520,000 fp16

typedef _Float16 v8h __attribute__((ext_vector_type(8)));
typedef float v16f __attribute__((ext_vector_type(16)));
typedef unsigned short ushort8v __attribute__((ext_vector_type(8)));
typedef unsigned short ushort4v __attribute__((ext_vector_type(4)));

__device__ __forceinline__ unsigned short f2h(float v) {
  _Float16 h = (_Float16)v;
  return *reinterpret_cast<const unsigned short*>(&h);
}
__device__ __forceinline__ float h2f(unsigned short u) {
  return (float)(*reinterpret_cast<const _Float16*>(&u));
}

__device__ __forceinline__ v8h exp8h(v8h x) {
  union { v8h v; __half2 h[4]; } u; u.v = x;
  #pragma unroll
  for (int i = 0; i < 4; i++) u.h[i] = h2exp(u.h[i]);
  return u.v;
}
__device__ __forceinline__ v8h rcp8h(v8h x) {
  union { v8h v; __half2 h[4]; } u; u.v = x;
  #pragma unroll
  for (int i = 0; i < 4; i++) u.h[i] = h2rcp(u.h[i]);
  return u.v;
}

// async global->LDS, 16B per lane; LDS dest = uniform base + lane*16
__device__ __forceinline__ void gload_lds16(const void* g, void* l) {
  __builtin_amdgcn_global_load_lds(
      (const __attribute__((address_space(1))) unsigned int*)g,
      (__attribute__((address_space(3))) unsigned int*)l, 16, 0, 0);
}

// channel-blocked CL addressing: [b][row][kb(4)][col][16], elems
__device__ __forceinline__ size_t clb(int b, int row, int kb, int col, int PD) {
  return ((((size_t)b * PD + row) * 4 + kb) * PD + col) * 16;
}

// batch-major XCD swizzle: 1024 blocks, XCD r gets batch r's rows in order
__device__ __forceinline__ void swz_bh(int& b, int& h) {
  int bid = blockIdx.x;
  int w = (bid & 7) * 128 + (bid >> 3);
  b = w >> 7; h = w & 127;
}

// ---------------- prep: weight packs + BN folds + border zeros --------------
// cdcm A-pack layout (18KB chunks): [d][kb][tap9][mh][512]
// other A-packs: [tap][kb][mh][lane*8+e], m=mh*32+(l&31), c=kb*16+(l>>5)*8+e
__global__ __launch_bounds__(256) void k_prep(
    const float* __restrict__ w1, const float* __restrict__ w5,
    const float* __restrict__ w7, const float* __restrict__ w9,
    const float* __restrict__ w11, const float* __restrict__ pww,
    const float* __restrict__ frw, const float* __restrict__ cw,
    const float* __restrict__ gww, const float* __restrict__ gwb,
    const float* __restrict__ gbg, const float* __restrict__ gbb,
    const float* __restrict__ gbm, const float* __restrict__ gbv,
    const float* __restrict__ ensw, const float* __restrict__ ensb,
    const float* __restrict__ bng, const float* __restrict__ bnb,
    const float* __restrict__ bnm, const float* __restrict__ bnv,
    unsigned short* __restrict__ apack, unsigned short* __restrict__ apinv,
    unsigned short* __restrict__ apens, unsigned short* __restrict__ appw1,
    unsigned short* __restrict__ appw, unsigned short* __restrict__ apfr,
    unsigned short* __restrict__ gwpk,
    unsigned short* __restrict__ apk, unsigned short* __restrict__ bpk,
    float* __restrict__ esc, float* __restrict__ ebi,
    unsigned short* __restrict__ ypad, unsigned short* __restrict__ spad)
{
  int id = blockIdx.x * 256 + threadIdx.x;
  if (id < 147456) {               // cdcm: chunked [d][kb][t9][mh][512]
    int c0 = id / 9216;            // ci = d*4 + kb
    int d = c0 >> 2, kb = c0 & 3;
    int r = id - c0 * 9216;
    int t9 = r / 1024;
    int r2 = r & 1023;
    int mh = r2 >> 9, l = (r2 >> 3) & 63, e = r2 & 7;
    int m = mh * 32 + (l & 31);
    int c = kb * 16 + (l >> 5) * 8 + e;
    const float* src = (d == 0) ? w5 : (d == 1) ? w7 : (d == 2) ? w9 : w11;
    apack[id] = f2h(src[(m * 64 + c) * 9 + t9]);
    return;
  }
  id -= 147456;
  if (id < 36864) {                // involution conv_w: 9 taps
    int e = id & 7, l = (id >> 3) & 63, mh = (id >> 9) & 1,
        kb = (id >> 10) & 3, tap = id >> 12;
    int m = mh * 32 + (l & 31);
    int c = kb * 16 + (l >> 5) * 8 + e;
    apinv[id] = f2h(cw[(m * 64 + c) * 9 + tap]);
    return;
  }
  id -= 36864;
  if (id < 36864) {                // ensemble mean weights: 9 taps
    int e = id & 7, l = (id >> 3) & 63, mh = (id >> 9) & 1,
        kb = (id >> 10) & 3, tap = id >> 12;
    int m = mh * 32 + (l & 31);
    int c = kb * 16 + (l >> 5) * 8 + e;
    float v = (ensw[((0 * 64 + m) * 64 + c) * 9 + tap] +
               ensw[((64 + m) * 64 + c) * 9 + tap] +
               ensw[((128 + m) * 64 + c) * 9 + tap]) * (1.f / 3.f);
    apens[id] = f2h(v);
    return;
  }
  id -= 36864;
  if (id < 4096) {                 // conv1 1x1
    int e = id & 7, l = (id >> 3) & 63, mh = (id >> 9) & 1, kb = (id >> 10) & 3;
    int m = mh * 32 + (l & 31);
    int c = kb * 16 + (l >> 5) * 8 + e;
    appw1[id] = f2h(w1[m * 64 + c]);
    return;
  }
  id -= 4096;
  if (id < 4096) {                 // dsc pointwise 1x1
    int e = id & 7, l = (id >> 3) & 63, mh = (id >> 9) & 1, kb = (id >> 10) & 3;
    int m = mh * 32 + (l & 31);
    int c = kb * 16 + (l >> 5) * 8 + e;
    appw[id] = f2h(pww[m * 64 + c]);
    return;
  }
  id -= 4096;
  if (id < 4096) {                 // fr 1x1
    int e = id & 7, l = (id >> 3) & 63, mh = (id >> 9) & 1, kb = (id >> 10) & 3;
    int m = mh * 32 + (l & 31);
    int c = kb * 16 + (l >> 5) * 8 + e;
    apfr[id] = f2h(frw[m * 64 + c]);
    return;
  }
  id -= 4096;
  if (id < 5184) {                 // packed gw weights [cblk8][tap81][ch8]
    int cblk = id / 648, r = id - cblk * 648;
    int tap = r >> 3, ch = r & 7;
    int c = cblk * 8 + ch;
    gwpk[id] = f2h(gww[c * 81 + tap]);
    return;
  }
  id -= 5184;
  if (id < 576) {                  // packed BN scale [cblk8][o9][ch8]
    int cblk = id / 72, r = id - cblk * 72;
    int o = r >> 3, ch = r & 7;
    int c = cblk * 8 + ch;
    float A = gbg[c * 9 + o] / sqrtf(gbv[c * 9 + o] + EPSV);
    apk[id] = f2h(A);
    return;
  }
  id -= 576;
  if (id < 576) {                  // packed BN shift
    int cblk = id / 72, r = id - cblk * 72;
    int o = r >> 3, ch = r & 7;
    int c = cblk * 8 + ch;
    float A = gbg[c * 9 + o] / sqrtf(gbv[c * 9 + o] + EPSV);
    float B = (gwb[c * 9 + o] - gbm[c * 9 + o]) * A + gbb[c * 9 + o];
    bpk[id] = f2h(B);
    return;
  }
  id -= 576;
  if (id < 64) {                   // final BN fold (+ mean ensemble bias)
    float s = bng[id] / sqrtf(bnv[id] + EPSV);
    esc[id] = s;
    float bm = (ensb[id] + ensb[64 + id] + ensb[128 + id]) * (1.f / 3.f);
    ebi[id] = (bm - bnm[id]) * s + bnb[id];
    return;
  }
  id -= 64;
  ushort8v z = {0, 0, 0, 0, 0, 0, 0, 0};
  const int perY = 22 * PR + 128 * 22;      // 6116: ypad border (pad 11)
  if (id < perY * Bn) {
    int b = id / perY; int r = id - b * perY;
    int tb = 22 * PR;
    int row, col;
    if (r < tb) {
      int rr = r / PR; col = r - rr * PR;
      row = (rr < 11) ? rr : (rr + 128);
    } else {
      int r2 = r - tb;
      row = 11 + r2 / 22;
      int cc = r2 % 22;
      col = (cc < 11) ? cc : (cc + 128);
    }
    #pragma unroll
    for (int kb = 0; kb < 4; kb++) {
      unsigned short* p = ypad + clb(b, row, kb, col, PR);
      *(ushort8v*)p = z;
      *(ushort8v*)(p + 8) = z;
    }
    return;
  }
  id -= perY * Bn;
  const int perS = 2 * PE + 256;            // 516: spad border (pad 1)
  if (id < perS * Bn) {
    int b = id / perS; int r = id - b * perS;
    int tb = 2 * PE;
    int row, col;
    if (r < tb) {
      int rr = r / PE; col = r - rr * PE;
      row = (rr < 1) ? 0 : 129;
    } else {
      int r2 = r - tb;
      row = 1 + r2 / 2;
      col = (r2 & 1) ? 129 : 0;
    }
    #pragma unroll
    for (int kb = 0; kb < 4; kb++) {
      unsigned short* p = spad + clb(b, row, kb, col, PE);
      *(ushort8v*)p = z;
      *(ushort8v*)(p + 8) = z;
    }
  }
}

// ---------------- stage 1: conv1x1(relu(x)) via MFMA, planar fp32 in --------
__global__ __launch_bounds__(256, 4) void k_pw1x(const float* __restrict__ x,
    const unsigned short* __restrict__ apw, const float* __restrict__ bias,
    unsigned short* __restrict__ ypad)
{
  int b, h; swz_bh(b, h);
  const int tid = threadIdx.x, wv = tid >> 6, l = tid & 63;
  const int ln31 = l & 31, g = l >> 5;
  const int px = wv * 32 + ln31;
  const float* xb = x + ((size_t)b * Cn) * Pn + h * Wn + px;
  v16f acc0, acc1;
  #pragma unroll
  for (int r = 0; r < 16; r++) { acc0[r] = 0.f; acc1[r] = 0.f; }
  const unsigned short* apl = apw + l * 8;
  #pragma unroll
  for (int kb = 0; kb < 4; kb++) {
    int c0 = kb * 16 + g * 8;
    v8h Bf;
    #pragma unroll
    for (int e = 0; e < 8; e++)
      Bf[e] = (_Float16)fmaxf(xb[(size_t)(c0 + e) * Pn], 0.f);
    v8h A0 = *(const v8h*)(apl + (kb * 2) * 512);
    v8h A1 = *(const v8h*)(apl + (kb * 2 + 1) * 512);
    acc0 = __builtin_amdgcn_mfma_f32_32x32x16_f16(A0, Bf, acc0, 0, 0, 0);
    acc1 = __builtin_amdgcn_mfma_f32_32x32x16_f16(A1, Bf, acc1, 0, 0, 0);
  }
  #pragma unroll
  for (int t = 0; t < 4; t++) {
    int c0 = 8 * t + 4 * g;
    int kb = c0 >> 4, sub = c0 & 15;
    ushort4v s0, s1;
    #pragma unroll
    for (int u = 0; u < 4; u++) {
      s0[u] = f2h(acc0[4 * t + u] + bias[c0 + u]);
      s1[u] = f2h(acc1[4 * t + u] + bias[c0 + u + 32]);
    }
    *(ushort4v*)(ypad + clb(b, h + 11, kb, px + 11, PR) + sub) = s0;
    *(ushort4v*)(ypad + clb(b, h + 11, kb + 2, px + 11, PR) + sub) = s1;
  }
}

// ---------------- stage 2: cdcm, persistent 16-wave block, pair phases ------
// grid 256, block 1024. 8 phases of (d, kb-pair) = 36 KB each, double
// buffered (72 KB LDS); A staged once per CU per phase (granules spread
// over waves: 0-3 take 3, rest 2); counted per-wave vmcnt, never 0
// mid-loop. 36 MFMA/wave per barrier pair hides staging + B latency.
__global__ __launch_bounds__(1024, 1) void k_cdcm_mfma(
    const unsigned short* __restrict__ ypad,
    const unsigned short* __restrict__ apack,
    unsigned short* __restrict__ spad)
{
  __shared__ __align__(16) unsigned short Abuf[2][18432];  // 2 x 36 KB
  const int bid = blockIdx.x;
  const int b = bid & 7, rg = bid >> 3;
  const int tid = threadIdx.x, wv = tid >> 6, l = tid & 63;
  const int ln31 = l & 31, g = l >> 5;
  const int h = rg * 4 + (wv >> 2);
  const int seg = (wv & 3) * 32;
  const int ng = (wv < 4) ? 3 : 2;   // granules this wave stages (36 total)

  // issue pair 0
  {
    const char* src = (const char*)apack;
    char* dst = (char*)&Abuf[0][0];
    for (int i = 0; i < ng; i++) {
      int off = (wv + i * 16) * 1024;
      gload_lds16(src + off + l * 16, dst + off);
    }
  }

  v16f acc0, acc1;
  #pragma unroll
  for (int r = 0; r < 16; r++) { acc0[r] = 0.f; acc1[r] = 0.f; }

  #pragma unroll
  for (int pp = 0; pp < 8; pp++) {
    const int d = pp >> 1, kbp = pp & 1;
    const int dil = 5 + 2 * d;
    if (pp < 7) {                  // prefetch next pair into other buffer
      const char* src = (const char*)(apack + (pp + 1) * 18432);
      char* dst = (char*)&Abuf[(pp + 1) & 1][0];
      for (int i = 0; i < ng; i++) {
        int off = (wv + i * 16) * 1024;
        gload_lds16(src + off + l * 16, dst + off);
      }
      if (wv < 4) asm volatile("s_waitcnt vmcnt(3)" ::: "memory");
      else        asm volatile("s_waitcnt vmcnt(2)" ::: "memory");
    } else {
      asm volatile("s_waitcnt vmcnt(0)" ::: "memory");
    }
    asm volatile("s_barrier" ::: "memory");

    __builtin_amdgcn_s_setprio(1);
    const unsigned short* abl = &Abuf[pp & 1][0] + l * 8;
    #pragma unroll
    for (int kbl = 0; kbl < 2; kbl++) {
      const int kb = kbp * 2 + kbl;
      #pragma unroll
      for (int ky = 0; ky < 3; ky++) {
        const int row = h + 11 + (ky - 1) * dil;
        #pragma unroll
        for (int kx = 0; kx < 3; kx++) {
          const int col = seg + ln31 + (kx - 1) * dil + 11;
          const int t9 = ky * 3 + kx;
          v8h Bf = *(const v8h*)(ypad + clb(b, row, kb, col, PR) + g * 8);
          const unsigned short* ap = abl + kbl * 9216 + t9 * 1024;
          v8h A0 = *(const v8h*)(ap);
          v8h A1 = *(const v8h*)(ap + 512);
          acc0 = __builtin_amdgcn_mfma_f32_32x32x16_f16(A0, Bf, acc0, 0, 0, 0);
          acc1 = __builtin_amdgcn_mfma_f32_32x32x16_f16(A1, Bf, acc1, 0, 0, 0);
        }
      }
    }
    __builtin_amdgcn_s_setprio(0);
    asm volatile("s_barrier" ::: "memory");  // waves done with buf[pp&1]
  }
  const int px = seg + ln31;
  #pragma unroll
  for (int t = 0; t < 4; t++) {
    int c0 = 8 * t + 4 * g;
    int kb = c0 >> 4, sub = c0 & 15;
    ushort4v s0, s1;
    #pragma unroll
    for (int u = 0; u < 4; u++) {
      s0[u] = f2h(acc0[4 * t + u]);
      s1[u] = f2h(acc1[4 * t + u]);
    }
    *(ushort4v*)(spad + clb(b, h + 1, kb, px + 1, PE) + sub) = s0;
    *(ushort4v*)(spad + clb(b, h + 1, kb + 2, px + 1, PE) + sub) = s1;
  }
}

// ---------------- stage 3: depthwise (VALU) + pointwise (MFMA) --------------
// Blocks h==0/h==1 also zero y2pad's pad-1 borders (safe: nothing reads
// y2pad until invol; border writes disjoint from all interior writes).
__global__ __launch_bounds__(256, 4) void k_dwpw_mfma(
    const unsigned short* __restrict__ spad,
    const float* __restrict__ dww, const float* __restrict__ dwb,
    const unsigned short* __restrict__ appw, const float* __restrict__ pwb,
    unsigned short* __restrict__ y2pad)
{
  __shared__ float wdw[576];
  __shared__ float bdw[64];
  const int tid = threadIdx.x;
  for (int t = tid; t < 576; t += 256) wdw[t] = dww[t];
  if (tid < 64) bdw[tid] = dwb[tid];
  __syncthreads();

  int b, h; swz_bh(b, h);

  ushort8v z = {0, 0, 0, 0, 0, 0, 0, 0};
  if (h == 0) {
    for (int px = tid; px < 260; px += 256) {
      int row = (px < 130) ? 0 : 129;
      int col = (px < 130) ? px : px - 130;
      #pragma unroll
      for (int kb = 0; kb < 4; kb++) {
        unsigned short* p = y2pad + clb(b, row, kb, col, PE);
        *(ushort8v*)p = z;
        *(ushort8v*)(p + 8) = z;
      }
    }
  } else if (h == 1) {
    int row = 1 + (tid & 127);
    int col = (tid >> 7) ? 129 : 0;
    #pragma unroll
    for (int kb = 0; kb < 4; kb++) {
      unsigned short* p = y2pad + clb(b, row, kb, col, PE);
      *(ushort8v*)p = z;
      *(ushort8v*)(p + 8) = z;
    }
  }

  const int wv = tid >> 6, l = tid & 63;
  const int ln31 = l & 31, g = l >> 5;
  const int w = wv * 32 + ln31;

  v16f acc0, acc1;
  #pragma unroll
  for (int r = 0; r < 16; r++) { acc0[r] = 0.f; acc1[r] = 0.f; }
  const unsigned short* apl = appw + l * 8;

  #pragma unroll
  for (int kb = 0; kb < 4; kb++) {
    const int c0 = kb * 16 + g * 8;
    v8h t[9];
    #pragma unroll
    for (int k = 0; k < 9; k++) {
      const int dy = k / 3 - 1, dx = k % 3 - 1;
      t[k] = *(const v8h*)(spad + clb(b, h + 1 + dy, kb, w + 1 + dx, PE) + g * 8);
    }
    v8h dvh;
    #pragma unroll
    for (int e = 0; e < 8; e++) {
      const int c = c0 + e;
      float a = 4.f * bdw[c];
      #pragma unroll
      for (int k = 0; k < 9; k++) a += wdw[c * 9 + k] * (float)t[k][e];
      dvh[e] = (_Float16)a;
    }
    v8h A0 = *(const v8h*)(apl + (kb * 2) * 512);
    v8h A1 = *(const v8h*)(apl + (kb * 2 + 1) * 512);
    acc0 = __builtin_amdgcn_mfma_f32_32x32x16_f16(A0, dvh, acc0, 0, 0, 0);
    acc1 = __builtin_amdgcn_mfma_f32_32x32x16_f16(A1, dvh, acc1, 0, 0, 0);
  }
  #pragma unroll
  for (int t = 0; t < 4; t++) {
    int c0 = 8 * t + 4 * g;
    int kb = c0 >> 4, sub = c0 & 15;
    ushort4v s0, s1;
    #pragma unroll
    for (int u = 0; u < 4; u++) {
      s0[u] = f2h(acc0[4 * t + u] + 4.f * pwb[c0 + u]);
      s1[u] = f2h(acc1[4 * t + u] + 4.f * pwb[c0 + u + 32]);
    }
    *(ushort4v*)(y2pad + clb(b, h + 1, kb, w + 1, PE) + sub) = s0;
    *(ushort4v*)(y2pad + clb(b, h + 1, kb + 2, w + 1, PE) + sub) = s1;
  }
}

// ---------------- stage 4: involution, packed-fp16 softmax + MFMA -----------
__global__ __launch_bounds__(256, 3) void k_invol_mfma(
    const unsigned short* __restrict__ y2pad,
    const unsigned short* __restrict__ gwpk,
    const unsigned short* __restrict__ apk,
    const unsigned short* __restrict__ bpk,
    const unsigned short* __restrict__ apinv,
    const float* __restrict__ cbias,
    unsigned short* __restrict__ ipad)
{
  __shared__ __align__(16) unsigned short gws[5184];  // [cblk8][tap81][ch8]
  __shared__ __align__(16) unsigned short As[576];    // [cblk8][o9][ch8]
  __shared__ __align__(16) unsigned short Bs[576];
  const int tid = threadIdx.x;
  for (int t = tid; t < 648; t += 256)
    ((ushort8v*)gws)[t] = ((const ushort8v*)gwpk)[t];
  if (tid < 72) {
    ((ushort8v*)As)[tid] = ((const ushort8v*)apk)[tid];
    ((ushort8v*)Bs)[tid] = ((const ushort8v*)bpk)[tid];
  }
  __syncthreads();

  int b, h; swz_bh(b, h);
  const int wv = tid >> 6, l = tid & 63;
  const int p32 = l & 31, g = l >> 5;
  const int w = wv * 32 + p32;

  v16f acc0, acc1;
  #pragma unroll
  for (int r = 0; r < 16; r++) { acc0[r] = 0.f; acc1[r] = 0.f; }

  for (int cb4 = 0; cb4 < 4; cb4++) {
    const int cblk = cb4 * 2 + g;
    const unsigned short* gwp = gws + cblk * 648;
    const unsigned short* Ap = As + cblk * 72;
    const unsigned short* Bp = Bs + cblk * 72;

    v8h pt[9];
    #pragma unroll
    for (int k = 0; k < 9; k++) {
      const int dy = k / 3 - 1, dx = k % 3 - 1;
      pt[k] = *(const v8h*)(y2pad + clb(b, h + 1 + dy, cb4, w + 1 + dx, PE) + g * 8);
    }
    // gw matmul + BN, all packed fp16 (weights broadcast from LDS)
    v8h s[9];
    #pragma unroll
    for (int o = 0; o < 9; o++) {
      v8h a = (*(const v8h*)(gwp + o * 72)) * pt[0];
      #pragma unroll
      for (int i = 1; i < 9; i++)
        a += (*(const v8h*)(gwp + o * 72 + i * 8)) * pt[i];
      s[o] = a * (*(const v8h*)(Ap + o * 8)) + (*(const v8h*)(Bp + o * 8));
    }
    // softmax over the 9 taps (shift-free: |s| << 1, fp16-safe)
    v8h esum = {0, 0, 0, 0, 0, 0, 0, 0};
    #pragma unroll
    for (int o = 0; o < 9; o++) { s[o] = exp8h(s[o]); esum += s[o]; }
    v8h inv = rcp8h(esum);
    #pragma unroll
    for (int k = 0; k < 9; k++) pt[k] = pt[k] * s[k] * inv;

    const unsigned short* ap = apinv + l * 8;
    __builtin_amdgcn_s_setprio(1);
    #pragma unroll
    for (int k = 0; k < 9; k++) {
      const unsigned short* a2 = ap + ((k * 4 + cb4) * 2) * 512;
      v8h A0 = *(const v8h*)(a2);
      v8h A1 = *(const v8h*)(a2 + 512);
      acc0 = __builtin_amdgcn_mfma_f32_32x32x16_f16(A0, pt[k], acc0, 0, 0, 0);
      acc1 = __builtin_amdgcn_mfma_f32_32x32x16_f16(A1, pt[k], acc1, 0, 0, 0);
    }
    __builtin_amdgcn_s_setprio(0);
  }
  #pragma unroll
  for (int t = 0; t < 4; t++) {
    int c0 = 8 * t + 4 * g;
    int kb = c0 >> 4, sub = c0 & 15;
    ushort4v s0, s1;
    #pragma unroll
    for (int u = 0; u < 4; u++) {
      s0[u] = f2h(acc0[4 * t + u] + cbias[c0 + u]);
      s1[u] = f2h(acc1[4 * t + u] + cbias[c0 + u + 32]);
    }
    *(ushort4v*)(ipad + clb(b, h, kb, w, 128) + sub) = s0;
    *(ushort4v*)(ipad + clb(b, h, kb + 2, w, 128) + sub) = s1;
  }
}

// ---------------- stage 5: fr 1x1 + residual (direct epilogue add) ----------
__global__ __launch_bounds__(256, 4) void k_fr_mfma(
    const unsigned short* __restrict__ ipad,
    const unsigned short* __restrict__ apfr,
    const float* __restrict__ bias,
    unsigned short* __restrict__ opad)
{
  int b, h; swz_bh(b, h);
  const int tid = threadIdx.x, wv = tid >> 6, l = tid & 63;
  const int ln31 = l & 31, g = l >> 5;
  const int px = wv * 32 + ln31;
  v16f acc0, acc1;
  #pragma unroll
  for (int r = 0; r < 16; r++) { acc0[r] = 0.f; acc1[r] = 0.f; }
  const unsigned short* apl = apfr + l * 8;
  #pragma unroll
  for (int kb = 0; kb < 4; kb++) {
    v8h Bf = *(const v8h*)(ipad + clb(b, h, kb, px, 128) + g * 8);
    v8h A0 = *(const v8h*)(apl + (kb * 2) * 512);
    v8h A1 = *(const v8h*)(apl + (kb * 2 + 1) * 512);
    acc0 = __builtin_amdgcn_mfma_f32_32x32x16_f16(A0, Bf, acc0, 0, 0, 0);
    acc1 = __builtin_amdgcn_mfma_f32_32x32x16_f16(A1, Bf, acc1, 0, 0, 0);
  }
  #pragma unroll
  for (int t = 0; t < 4; t++) {
    int c0 = 8 * t + 4 * g;
    int kb = c0 >> 4, sub = c0 & 15;
    // residual values live at exactly the epilogue addresses
    ushort4v r0 = *(const ushort4v*)(ipad + clb(b, h, kb, px, 128) + sub);
    ushort4v r1 = *(const ushort4v*)(ipad + clb(b, h, kb + 2, px, 128) + sub);
    ushort4v s0, s1;
    #pragma unroll
    for (int u = 0; u < 4; u++) {
      s0[u] = f2h(acc0[4 * t + u] + bias[c0 + u] + h2f(r0[u]));
      s1[u] = f2h(acc1[4 * t + u] + bias[c0 + u + 32] + h2f(r1[u]));
    }
    *(ushort4v*)(opad + clb(b, h + 1, kb, px + 1, PE) + sub) = s0;
    *(ushort4v*)(opad + clb(b, h + 1, kb + 2, px + 1, PE) + sub) = s1;
  }
}

// ---------------- stage 6: ensemble conv3x3, 2 rows/block, LDS weights ------
__global__ __launch_bounds__(256) void k_ens_mfma(
    const unsigned short* __restrict__ opad,
    const unsigned short* __restrict__ apens,
    const float* __restrict__ esc, const float* __restrict__ ebi,
    float* __restrict__ out)
{
  __shared__ __align__(16) unsigned short Abuf[36864];  // 72 KB: 9 taps
  const int tid = threadIdx.x;
  {
    const ushort8v* src = (const ushort8v*)apens;
    ushort8v* dst = (ushort8v*)Abuf;
    #pragma unroll
    for (int it = 0; it < 18; it++)
      dst[tid + it * 256] = src[tid + it * 256];
  }
  __syncthreads();

  const int bid = blockIdx.x;
  const int b = bid & 7, h0 = (bid >> 3) * 2;
  const int wv = tid >> 6, l = tid & 63;
  const int ln31 = l & 31, g = l >> 5;

  v16f a00, a01, a10, a11;
  #pragma unroll
  for (int r = 0; r < 16; r++) { a00[r] = 0.f; a01[r] = 0.f; a10[r] = 0.f; a11[r] = 0.f; }

  const unsigned short* abl = Abuf + l * 8;

  #pragma unroll
  for (int ky = 0; ky < 3; ky++) {
    #pragma unroll
    for (int kx = 0; kx < 3; kx++) {
      const int tap = ky * 3 + kx;
      const int r0 = h0 + ky;              // (h0+1) + (ky-1)
      const int col = wv * 32 + ln31 + kx; // (+1) + (kx-1)
      const unsigned short* ap = abl + tap * 4096;
      #pragma unroll
      for (int kb = 0; kb < 4; kb++) {
        v8h B0 = *(const v8h*)(opad + clb(b, r0, kb, col, PE) + g * 8);
        v8h B1 = *(const v8h*)(opad + clb(b, r0 + 1, kb, col, PE) + g * 8);
        v8h A0 = *(const v8h*)(ap + kb * 1024);
        v8h A1 = *(const v8h*)(ap + kb * 1024 + 512);
        a00 = __builtin_amdgcn_mfma_f32_32x32x16_f16(A0, B0, a00, 0, 0, 0);
        a01 = __builtin_amdgcn_mfma_f32_32x32x16_f16(A1, B0, a01, 0, 0, 0);
        a10 = __builtin_amdgcn_mfma_f32_32x32x16_f16(A0, B1, a10, 0, 0, 0);
        a11 = __builtin_amdgcn_mfma_f32_32x32x16_f16(A1, B1, a11, 0, 0, 0);
      }
    }
  }
  float* sp0 = out + ((size_t)b * Cn) * Pn + h0 * Wn + wv * 32 + ln31;
  float* sp1 = sp0 + Wn;
  #pragma unroll
  for (int r = 0; r < 16; r++) {
    int o0 = (r & 3) + 8 * (r >> 2) + 4 * g;
    float e0 = esc[o0], e1 = esc[o0 + 32];
    float i0 = ebi[o0], i1 = ebi[o0 + 32];
    sp0[(size_t)o0 * Pn] = fmaxf(a00[r] * e0 + i0, 0.f);
    sp0[(size_t)(o0 + 32) * Pn] = fmaxf(a01[r] * e1 + i1, 0.f);
    sp1[(size_t)o0 * Pn] = fmaxf(a10[r] * e0 + i0, 0.f);
    sp1[(size_t)(o0 + 32) * Pn] = fmaxf(a11[r] * e1 + i1, 0.f);
  }
}

extern "C" void kernel_launch(void* const* d_in, const int* in_sizes, int n_in,
                              void* d_out, int out_size, void* d_ws, size_t ws_size,
                              hipStream_t stream)
{
  const float* x    = (const float*)d_in[0];
  const float* w1   = (const float*)d_in[1];
  const float* b1   = (const float*)d_in[2];
  const float* w5   = (const float*)d_in[3];
  const float* w7   = (const float*)d_in[4];
  const float* w9   = (const float*)d_in[5];
  const float* w11  = (const float*)d_in[6];
  const float* dww  = (const float*)d_in[7];
  const float* dwb  = (const float*)d_in[8];
  const float* pww  = (const float*)d_in[9];
  const float* pwb  = (const float*)d_in[10];
  const float* gww  = (const float*)d_in[11];
  const float* gwb  = (const float*)d_in[12];
  const float* gbg  = (const float*)d_in[13];
  const float* gbb  = (const float*)d_in[14];
  const float* gbm  = (const float*)d_in[15];
  const float* gbv  = (const float*)d_in[16];
  const float* cw   = (const float*)d_in[17];
  const float* cb   = (const float*)d_in[18];
  const float* frw  = (const float*)d_in[19];
  const float* frb  = (const float*)d_in[20];
  const float* ensw = (const float*)d_in[21];
  const float* ensb = (const float*)d_in[22];
  const float* bng  = (const float*)d_in[23];
  const float* bnb  = (const float*)d_in[24];
  const float* bnm  = (const float*)d_in[25];
  const float* bnv  = (const float*)d_in[26];

  // ws: ypad (pad-11) region, overlaid later by y2pad then opad (pad-1)
  unsigned short* wsu   = (unsigned short*)d_ws;
  unsigned short* ypad  = wsu;
  unsigned short* y2pad = wsu;
  unsigned short* opad  = wsu;
  unsigned short* apack = wsu + YPAD_ELEMS;         // 147456
  unsigned short* apinv = apack + 147456;           // 36864
  unsigned short* apens = apinv + 36864;            // 36864
  unsigned short* appw1 = apens + 36864;            // 4096
  unsigned short* appw  = appw1 + 4096;             // 4096
  unsigned short* apfr  = appw + 4096;              // 4096
  unsigned short* gwpk  = apfr + 4096;              // 5184
  unsigned short* apk   = gwpk + 5184;              // 576
  unsigned short* bpk   = apk + 576;                // 576
  float* esc = (float*)(bpk + 576);                 // 64
  float* ebi = esc + 64;                            // 64

  // d_out: spad (fp16 blocked-CL pad-1) -> ipad (blocked-CL) -> planar fp32
  unsigned short* spad = (unsigned short*)d_out;
  unsigned short* ipad = (unsigned short*)d_out;
  float* D = (float*)d_out;

  // prep also zeroes ypad borders (pad 11) and spad borders (pad 1)
  k_prep<<<1145, 256, 0, stream>>>(w1, w5, w7, w9, w11, pww, frw, cw,
                                   gww, gwb, gbg, gbb, gbm, gbv, ensw, ensb,
                                   bng, bnb, bnm, bnv,
                                   apack, apinv, apens, appw1, appw, apfr,
                                   gwpk, apk, bpk, esc, ebi,
                                   ypad, spad);

  // 1) ypad = conv1x1(relu(x))           x (planar f32) -> ypad (blocked CL)
  k_pw1x<<<1024, 256, 0, stream>>>(x, appw1, b1, ypad);
  // 2) spad = sum_d dilconv_d(y)         ypad -> spad (d_out, pad-1)
  k_cdcm_mfma<<<256, 1024, 0, stream>>>(ypad, apack, spad);
  // 3) y2pad = PW(DW(spad))              spad -> y2pad (ws, pad-1)
  //    (blocks h=0/1 also zero y2pad borders; ypad is dead by now)
  k_dwpw_mfma<<<1024, 256, 0, stream>>>(spad, dww, dwb, appw, pwb, y2pad);
  // 4) ipad = involution(y2pad)          y2pad -> ipad (d_out)
  k_invol_mfma<<<1024, 256, 0, stream>>>(y2pad, gwpk, apk, bpk, apinv, cb, ipad);
  // 5) opad = fr(ipad) + ipad            ipad -> opad (ws, pad-1)
  k_fr_mfma<<<1024, 256, 0, stream>>>(ipad, apfr, frb, opad);
  // 6) out = relu(BN(ens3x3(opad)))      opad -> D (planar fp32)
  k_ens_mfma<<<512, 256, 0, stream>>>(opad, apens, esc, ebi, D);
}

// Round 18
// 146.204 us; speedup vs baseline: 1.0552x; 1.0456x over previous
//
#include <hip/hip_runtime.h>
#include <hip/hip_bf16.h>
#include <hip/hip_fp16.h>

#define EPSV 1e-5f
#define Bn 8
#define Cn 64
#define Hn 128
#define Wn 128
#define Pn (Hn*Wn)          // 16384
#define PR 150              // cdcm pad: 11 + 128 + 11
#define PE 130              // 1-pad: 1 + 128 + 1
#define YPAD_ELEMS (Bn*PR*PR*Cn)   // 11,520,000 fp16

typedef _Float16 v8h __attribute__((ext_vector_type(8)));
typedef float v16f __attribute__((ext_vector_type(16)));
typedef unsigned short ushort8v __attribute__((ext_vector_type(8)));
typedef unsigned short ushort4v __attribute__((ext_vector_type(4)));

__device__ __forceinline__ unsigned short f2h(float v) {
  _Float16 h = (_Float16)v;
  return *reinterpret_cast<const unsigned short*>(&h);
}
__device__ __forceinline__ float h2f(unsigned short u) {
  return (float)(*reinterpret_cast<const _Float16*>(&u));
}

__device__ __forceinline__ v8h exp8h(v8h x) {
  union { v8h v; __half2 h[4]; } u; u.v = x;
  #pragma unroll
  for (int i = 0; i < 4; i++) u.h[i] = h2exp(u.h[i]);
  return u.v;
}
__device__ __forceinline__ v8h rcp8h(v8h x) {
  union { v8h v; __half2 h[4]; } u; u.v = x;
  #pragma unroll
  for (int i = 0; i < 4; i++) u.h[i] = h2rcp(u.h[i]);
  return u.v;
}

// async global->LDS, 16B per lane; LDS dest = uniform base + lane*16
__device__ __forceinline__ void gload_lds16(const void* g, void* l) {
  __builtin_amdgcn_global_load_lds(
      (const __attribute__((address_space(1))) unsigned int*)g,
      (__attribute__((address_space(3))) unsigned int*)l, 16, 0, 0);
}

// channel-blocked CL addressing: [b][row][kb(4)][col][16], elems
__device__ __forceinline__ size_t clb(int b, int row, int kb, int col, int PD) {
  return ((((size_t)b * PD + row) * 4 + kb) * PD + col) * 16;
}

// batch-major XCD swizzle: 1024 blocks, XCD r gets batch r's rows in order
__device__ __forceinline__ void swz_bh(int& b, int& h) {
  int bid = blockIdx.x;
  int w = (bid & 7) * 128 + (bid >> 3);
  b = w >> 7; h = w & 127;
}

// ---------------- prep: weight packs + BN folds + border zeros --------------
// cdcm A-pack layout (18KB chunks): [d][kb][tap9][mh][512]
// other A-packs: [tap][kb][mh][lane*8+e], m=mh*32+(l&31), c=kb*16+(l>>5)*8+e
__global__ __launch_bounds__(256) void k_prep(
    const float* __restrict__ w1, const float* __restrict__ w5,
    const float* __restrict__ w7, const float* __restrict__ w9,
    const float* __restrict__ w11, const float* __restrict__ pww,
    const float* __restrict__ frw, const float* __restrict__ cw,
    const float* __restrict__ gww, const float* __restrict__ gwb,
    const float* __restrict__ gbg, const float* __restrict__ gbb,
    const float* __restrict__ gbm, const float* __restrict__ gbv,
    const float* __restrict__ ensw, const float* __restrict__ ensb,
    const float* __restrict__ bng, const float* __restrict__ bnb,
    const float* __restrict__ bnm, const float* __restrict__ bnv,
    unsigned short* __restrict__ apack, unsigned short* __restrict__ apinv,
    unsigned short* __restrict__ apens, unsigned short* __restrict__ appw1,
    unsigned short* __restrict__ appw, unsigned short* __restrict__ apfr,
    unsigned short* __restrict__ gwpk,
    unsigned short* __restrict__ apk, unsigned short* __restrict__ bpk,
    float* __restrict__ esc, float* __restrict__ ebi,
    unsigned short* __restrict__ ypad, unsigned short* __restrict__ spad)
{
  int id = blockIdx.x * 256 + threadIdx.x;
  if (id < 147456) {               // cdcm: chunked [d][kb][t9][mh][512]
    int c0 = id / 9216;            // ci = d*4 + kb
    int d = c0 >> 2, kb = c0 & 3;
    int r = id - c0 * 9216;
    int t9 = r / 1024;
    int r2 = r & 1023;
    int mh = r2 >> 9, l = (r2 >> 3) & 63, e = r2 & 7;
    int m = mh * 32 + (l & 31);
    int c = kb * 16 + (l >> 5) * 8 + e;
    const float* src = (d == 0) ? w5 : (d == 1) ? w7 : (d == 2) ? w9 : w11;
    apack[id] = f2h(src[(m * 64 + c) * 9 + t9]);
    return;
  }
  id -= 147456;
  if (id < 36864) {                // involution conv_w: 9 taps
    int e = id & 7, l = (id >> 3) & 63, mh = (id >> 9) & 1,
        kb = (id >> 10) & 3, tap = id >> 12;
    int m = mh * 32 + (l & 31);
    int c = kb * 16 + (l >> 5) * 8 + e;
    apinv[id] = f2h(cw[(m * 64 + c) * 9 + tap]);
    return;
  }
  id -= 36864;
  if (id < 36864) {                // ensemble mean weights: 9 taps
    int e = id & 7, l = (id >> 3) & 63, mh = (id >> 9) & 1,
        kb = (id >> 10) & 3, tap = id >> 12;
    int m = mh * 32 + (l & 31);
    int c = kb * 16 + (l >> 5) * 8 + e;
    float v = (ensw[((0 * 64 + m) * 64 + c) * 9 + tap] +
               ensw[((64 + m) * 64 + c) * 9 + tap] +
               ensw[((128 + m) * 64 + c) * 9 + tap]) * (1.f / 3.f);
    apens[id] = f2h(v);
    return;
  }
  id -= 36864;
  if (id < 4096) {                 // conv1 1x1
    int e = id & 7, l = (id >> 3) & 63, mh = (id >> 9) & 1, kb = (id >> 10) & 3;
    int m = mh * 32 + (l & 31);
    int c = kb * 16 + (l >> 5) * 8 + e;
    appw1[id] = f2h(w1[m * 64 + c]);
    return;
  }
  id -= 4096;
  if (id < 4096) {                 // dsc pointwise 1x1
    int e = id & 7, l = (id >> 3) & 63, mh = (id >> 9) & 1, kb = (id >> 10) & 3;
    int m = mh * 32 + (l & 31);
    int c = kb * 16 + (l >> 5) * 8 + e;
    appw[id] = f2h(pww[m * 64 + c]);
    return;
  }
  id -= 4096;
  if (id < 4096) {                 // fr 1x1
    int e = id & 7, l = (id >> 3) & 63, mh = (id >> 9) & 1, kb = (id >> 10) & 3;
    int m = mh * 32 + (l & 31);
    int c = kb * 16 + (l >> 5) * 8 + e;
    apfr[id] = f2h(frw[m * 64 + c]);
    return;
  }
  id -= 4096;
  if (id < 5184) {                 // packed gw weights [cblk8][tap81][ch8]
    int cblk = id / 648, r = id - cblk * 648;
    int tap = r >> 3, ch = r & 7;
    int c = cblk * 8 + ch;
    gwpk[id] = f2h(gww[c * 81 + tap]);
    return;
  }
  id -= 5184;
  if (id < 576) {                  // packed BN scale [cblk8][o9][ch8]
    int cblk = id / 72, r = id - cblk * 72;
    int o = r >> 3, ch = r & 7;
    int c = cblk * 8 + ch;
    float A = gbg[c * 9 + o] / sqrtf(gbv[c * 9 + o] + EPSV);
    apk[id] = f2h(A);
    return;
  }
  id -= 576;
  if (id < 576) {                  // packed BN shift
    int cblk = id / 72, r = id - cblk * 72;
    int o = r >> 3, ch = r & 7;
    int c = cblk * 8 + ch;
    float A = gbg[c * 9 + o] / sqrtf(gbv[c * 9 + o] + EPSV);
    float B = (gwb[c * 9 + o] - gbm[c * 9 + o]) * A + gbb[c * 9 + o];
    bpk[id] = f2h(B);
    return;
  }
  id -= 576;
  if (id < 64) {                   // final BN fold (+ mean ensemble bias)
    float s = bng[id] / sqrtf(bnv[id] + EPSV);
    esc[id] = s;
    float bm = (ensb[id] + ensb[64 + id] + ensb[128 + id]) * (1.f / 3.f);
    ebi[id] = (bm - bnm[id]) * s + bnb[id];
    return;
  }
  id -= 64;
  ushort8v z = {0, 0, 0, 0, 0, 0, 0, 0};
  const int perY = 22 * PR + 128 * 22;      // 6116: ypad border (pad 11)
  if (id < perY * Bn) {
    int b = id / perY; int r = id - b * perY;
    int tb = 22 * PR;
    int row, col;
    if (r < tb) {
      int rr = r / PR; col = r - rr * PR;
      row = (rr < 11) ? rr : (rr + 128);
    } else {
      int r2 = r - tb;
      row = 11 + r2 / 22;
      int cc = r2 % 22;
      col = (cc < 11) ? cc : (cc + 128);
    }
    #pragma unroll
    for (int kb = 0; kb < 4; kb++) {
      unsigned short* p = ypad + clb(b, row, kb, col, PR);
      *(ushort8v*)p = z;
      *(ushort8v*)(p + 8) = z;
    }
    return;
  }
  id -= perY * Bn;
  const int perS = 2 * PE + 256;            // 516: spad border (pad 1)
  if (id < perS * Bn) {
    int b = id / perS; int r = id - b * perS;
    int tb = 2 * PE;
    int row, col;
    if (r < tb) {
      int rr = r / PE; col = r - rr * PE;
      row = (rr < 1) ? 0 : 129;
    } else {
      int r2 = r - tb;
      row = 1 + r2 / 2;
      col = (r2 & 1) ? 129 : 0;
    }
    #pragma unroll
    for (int kb = 0; kb < 4; kb++) {
      unsigned short* p = spad + clb(b, row, kb, col, PE);
      *(ushort8v*)p = z;
      *(ushort8v*)(p + 8) = z;
    }
  }
}

// ---------------- stage 1: conv1x1(relu(x)) via MFMA, planar fp32 in --------
__global__ __launch_bounds__(256, 4) void k_pw1x(const float* __restrict__ x,
    const unsigned short* __restrict__ apw, const float* __restrict__ bias,
    unsigned short* __restrict__ ypad)
{
  int b, h; swz_bh(b, h);
  const int tid = threadIdx.x, wv = tid >> 6, l = tid & 63;
  const int ln31 = l & 31, g = l >> 5;
  const int px = wv * 32 + ln31;
  const float* xb = x + ((size_t)b * Cn) * Pn + h * Wn + px;
  v16f acc0, acc1;
  #pragma unroll
  for (int r = 0; r < 16; r++) { acc0[r] = 0.f; acc1[r] = 0.f; }
  const unsigned short* apl = apw + l * 8;
  #pragma unroll
  for (int kb = 0; kb < 4; kb++) {
    int c0 = kb * 16 + g * 8;
    v8h Bf;
    #pragma unroll
    for (int e = 0; e < 8; e++)
      Bf[e] = (_Float16)fmaxf(xb[(size_t)(c0 + e) * Pn], 0.f);
    v8h A0 = *(const v8h*)(apl + (kb * 2) * 512);
    v8h A1 = *(const v8h*)(apl + (kb * 2 + 1) * 512);
    acc0 = __builtin_amdgcn_mfma_f32_32x32x16_f16(A0, Bf, acc0, 0, 0, 0);
    acc1 = __builtin_amdgcn_mfma_f32_32x32x16_f16(A1, Bf, acc1, 0, 0, 0);
  }
  #pragma unroll
  for (int t = 0; t < 4; t++) {
    int c0 = 8 * t + 4 * g;
    int kb = c0 >> 4, sub = c0 & 15;
    ushort4v s0, s1;
    #pragma unroll
    for (int u = 0; u < 4; u++) {
      s0[u] = f2h(acc0[4 * t + u] + bias[c0 + u]);
      s1[u] = f2h(acc1[4 * t + u] + bias[c0 + u + 32]);
    }
    *(ushort4v*)(ypad + clb(b, h + 11, kb, px + 11, PR) + sub) = s0;
    *(ushort4v*)(ypad + clb(b, h + 11, kb + 2, px + 11, PR) + sub) = s1;
  }
}

// ---------------- stage 2: cdcm, persistent 16-wave block (1/CU) ------------
// grid 256, block 1024. bid&7 = batch (XCD), bid>>3 = row-group of 4 rows.
// Wave w: row rg*4+(w>>2), px (w&3)*32..+31. 16 chunks (d,kb) of 18KB,
// double-buffered; A staged ONCE per CU per chunk (granule w per wave,
// waves 0-1 take 2); counted per-wave vmcnt, never 0 mid-loop.
__global__ __launch_bounds__(1024, 1) void k_cdcm_mfma(
    const unsigned short* __restrict__ ypad,
    const unsigned short* __restrict__ apack,
    unsigned short* __restrict__ spad)
{
  __shared__ __align__(16) unsigned short Abuf[2][9216];  // 2 x 18 KB
  const int bid = blockIdx.x;
  const int b = bid & 7, rg = bid >> 3;
  const int tid = threadIdx.x, wv = tid >> 6, l = tid & 63;
  const int ln31 = l & 31, g = l >> 5;
  const int h = rg * 4 + (wv >> 2);
  const int seg = (wv & 3) * 32;
  const int ng = (wv < 2) ? 2 : 1;   // granules this wave stages (18 total)

  // issue chunk 0
  {
    const char* src = (const char*)apack;
    char* dst = (char*)&Abuf[0][0];
    for (int i = 0; i < ng; i++) {
      int off = (wv + i * 16) * 1024;
      gload_lds16(src + off + l * 16, dst + off);
    }
  }

  v16f acc0, acc1;
  #pragma unroll
  for (int r = 0; r < 16; r++) { acc0[r] = 0.f; acc1[r] = 0.f; }

  #pragma unroll
  for (int d = 0; d < 4; d++) {
    const int dil = 5 + 2 * d;
    #pragma unroll
    for (int kb = 0; kb < 4; kb++) {
      const int ci = d * 4 + kb;
      if (ci < 15) {               // prefetch next chunk into other buffer
        const char* src = (const char*)(apack + (ci + 1) * 9216);
        char* dst = (char*)&Abuf[(ci + 1) & 1][0];
        for (int i = 0; i < ng; i++) {
          int off = (wv + i * 16) * 1024;
          gload_lds16(src + off + l * 16, dst + off);
        }
        if (wv < 2) asm volatile("s_waitcnt vmcnt(2)" ::: "memory");
        else        asm volatile("s_waitcnt vmcnt(1)" ::: "memory");
      } else {
        asm volatile("s_waitcnt vmcnt(0)" ::: "memory");
      }
      asm volatile("s_barrier" ::: "memory");

      __builtin_amdgcn_s_setprio(1);
      const unsigned short* abl = &Abuf[ci & 1][0] + l * 8;
      #pragma unroll
      for (int ky = 0; ky < 3; ky++) {
        const int row = h + 11 + (ky - 1) * dil;
        #pragma unroll
        for (int kx = 0; kx < 3; kx++) {
          const int col = seg + ln31 + (kx - 1) * dil + 11;
          const int t9 = ky * 3 + kx;
          v8h Bf = *(const v8h*)(ypad + clb(b, row, kb, col, PR) + g * 8);
          const unsigned short* ap = abl + t9 * 1024;
          v8h A0 = *(const v8h*)(ap);
          v8h A1 = *(const v8h*)(ap + 512);
          acc0 = __builtin_amdgcn_mfma_f32_32x32x16_f16(A0, Bf, acc0, 0, 0, 0);
          acc1 = __builtin_amdgcn_mfma_f32_32x32x16_f16(A1, Bf, acc1, 0, 0, 0);
        }
      }
      __builtin_amdgcn_s_setprio(0);
      asm volatile("s_barrier" ::: "memory");  // waves done with buf[ci&1]
    }
  }
  const int px = seg + ln31;
  #pragma unroll
  for (int t = 0; t < 4; t++) {
    int c0 = 8 * t + 4 * g;
    int kb = c0 >> 4, sub = c0 & 15;
    ushort4v s0, s1;
    #pragma unroll
    for (int u = 0; u < 4; u++) {
      s0[u] = f2h(acc0[4 * t + u]);
      s1[u] = f2h(acc1[4 * t + u]);
    }
    *(ushort4v*)(spad + clb(b, h + 1, kb, px + 1, PE) + sub) = s0;
    *(ushort4v*)(spad + clb(b, h + 1, kb + 2, px + 1, PE) + sub) = s1;
  }
}

// ---------------- stage 3: depthwise (VALU) + pointwise (MFMA) --------------
// Blocks h==0/h==1 also zero y2pad's pad-1 borders (safe: nothing reads
// y2pad until invol; border writes disjoint from all interior writes).
__global__ __launch_bounds__(256, 4) void k_dwpw_mfma(
    const unsigned short* __restrict__ spad,
    const float* __restrict__ dww, const float* __restrict__ dwb,
    const unsigned short* __restrict__ appw, const float* __restrict__ pwb,
    unsigned short* __restrict__ y2pad)
{
  __shared__ float wdw[576];
  __shared__ float bdw[64];
  const int tid = threadIdx.x;
  for (int t = tid; t < 576; t += 256) wdw[t] = dww[t];
  if (tid < 64) bdw[tid] = dwb[tid];
  __syncthreads();

  int b, h; swz_bh(b, h);

  ushort8v z = {0, 0, 0, 0, 0, 0, 0, 0};
  if (h == 0) {
    for (int px = tid; px < 260; px += 256) {
      int row = (px < 130) ? 0 : 129;
      int col = (px < 130) ? px : px - 130;
      #pragma unroll
      for (int kb = 0; kb < 4; kb++) {
        unsigned short* p = y2pad + clb(b, row, kb, col, PE);
        *(ushort8v*)p = z;
        *(ushort8v*)(p + 8) = z;
      }
    }
  } else if (h == 1) {
    int row = 1 + (tid & 127);
    int col = (tid >> 7) ? 129 : 0;
    #pragma unroll
    for (int kb = 0; kb < 4; kb++) {
      unsigned short* p = y2pad + clb(b, row, kb, col, PE);
      *(ushort8v*)p = z;
      *(ushort8v*)(p + 8) = z;
    }
  }

  const int wv = tid >> 6, l = tid & 63;
  const int ln31 = l & 31, g = l >> 5;
  const int w = wv * 32 + ln31;

  v16f acc0, acc1;
  #pragma unroll
  for (int r = 0; r < 16; r++) { acc0[r] = 0.f; acc1[r] = 0.f; }
  const unsigned short* apl = appw + l * 8;

  #pragma unroll
  for (int kb = 0; kb < 4; kb++) {
    const int c0 = kb * 16 + g * 8;
    v8h t[9];
    #pragma unroll
    for (int k = 0; k < 9; k++) {
      const int dy = k / 3 - 1, dx = k % 3 - 1;
      t[k] = *(const v8h*)(spad + clb(b, h + 1 + dy, kb, w + 1 + dx, PE) + g * 8);
    }
    v8h dvh;
    #pragma unroll
    for (int e = 0; e < 8; e++) {
      const int c = c0 + e;
      float a = 4.f * bdw[c];
      #pragma unroll
      for (int k = 0; k < 9; k++) a += wdw[c * 9 + k] * (float)t[k][e];
      dvh[e] = (_Float16)a;
    }
    v8h A0 = *(const v8h*)(apl + (kb * 2) * 512);
    v8h A1 = *(const v8h*)(apl + (kb * 2 + 1) * 512);
    acc0 = __builtin_amdgcn_mfma_f32_32x32x16_f16(A0, dvh, acc0, 0, 0, 0);
    acc1 = __builtin_amdgcn_mfma_f32_32x32x16_f16(A1, dvh, acc1, 0, 0, 0);
  }
  #pragma unroll
  for (int t = 0; t < 4; t++) {
    int c0 = 8 * t + 4 * g;
    int kb = c0 >> 4, sub = c0 & 15;
    ushort4v s0, s1;
    #pragma unroll
    for (int u = 0; u < 4; u++) {
      s0[u] = f2h(acc0[4 * t + u] + 4.f * pwb[c0 + u]);
      s1[u] = f2h(acc1[4 * t + u] + 4.f * pwb[c0 + u + 32]);
    }
    *(ushort4v*)(y2pad + clb(b, h + 1, kb, w + 1, PE) + sub) = s0;
    *(ushort4v*)(y2pad + clb(b, h + 1, kb + 2, w + 1, PE) + sub) = s1;
  }
}

// ---------------- stage 4: involution, packed-fp16 softmax + MFMA -----------
__global__ __launch_bounds__(256, 3) void k_invol_mfma(
    const unsigned short* __restrict__ y2pad,
    const unsigned short* __restrict__ gwpk,
    const unsigned short* __restrict__ apk,
    const unsigned short* __restrict__ bpk,
    const unsigned short* __restrict__ apinv,
    const float* __restrict__ cbias,
    unsigned short* __restrict__ ipad)
{
  __shared__ __align__(16) unsigned short gws[5184];  // [cblk8][tap81][ch8]
  __shared__ __align__(16) unsigned short As[576];    // [cblk8][o9][ch8]
  __shared__ __align__(16) unsigned short Bs[576];
  const int tid = threadIdx.x;
  for (int t = tid; t < 648; t += 256)
    ((ushort8v*)gws)[t] = ((const ushort8v*)gwpk)[t];
  if (tid < 72) {
    ((ushort8v*)As)[tid] = ((const ushort8v*)apk)[tid];
    ((ushort8v*)Bs)[tid] = ((const ushort8v*)bpk)[tid];
  }
  __syncthreads();

  int b, h; swz_bh(b, h);
  const int wv = tid >> 6, l = tid & 63;
  const int p32 = l & 31, g = l >> 5;
  const int w = wv * 32 + p32;

  v16f acc0, acc1;
  #pragma unroll
  for (int r = 0; r < 16; r++) { acc0[r] = 0.f; acc1[r] = 0.f; }

  for (int cb4 = 0; cb4 < 4; cb4++) {
    const int cblk = cb4 * 2 + g;
    const unsigned short* gwp = gws + cblk * 648;
    const unsigned short* Ap = As + cblk * 72;
    const unsigned short* Bp = Bs + cblk * 72;

    v8h pt[9];
    #pragma unroll
    for (int k = 0; k < 9; k++) {
      const int dy = k / 3 - 1, dx = k % 3 - 1;
      pt[k] = *(const v8h*)(y2pad + clb(b, h + 1 + dy, cb4, w + 1 + dx, PE) + g * 8);
    }
    // gw matmul + BN, all packed fp16 (weights broadcast from LDS)
    v8h s[9];
    #pragma unroll
    for (int o = 0; o < 9; o++) {
      v8h a = (*(const v8h*)(gwp + o * 72)) * pt[0];
      #pragma unroll
      for (int i = 1; i < 9; i++)
        a += (*(const v8h*)(gwp + o * 72 + i * 8)) * pt[i];
      s[o] = a * (*(const v8h*)(Ap + o * 8)) + (*(const v8h*)(Bp + o * 8));
    }
    // softmax over the 9 taps (shift-free: |s| << 1, fp16-safe)
    v8h esum = {0, 0, 0, 0, 0, 0, 0, 0};
    #pragma unroll
    for (int o = 0; o < 9; o++) { s[o] = exp8h(s[o]); esum += s[o]; }
    v8h inv = rcp8h(esum);
    #pragma unroll
    for (int k = 0; k < 9; k++) pt[k] = pt[k] * s[k] * inv;

    const unsigned short* ap = apinv + l * 8;
    __builtin_amdgcn_s_setprio(1);
    #pragma unroll
    for (int k = 0; k < 9; k++) {
      const unsigned short* a2 = ap + ((k * 4 + cb4) * 2) * 512;
      v8h A0 = *(const v8h*)(a2);
      v8h A1 = *(const v8h*)(a2 + 512);
      acc0 = __builtin_amdgcn_mfma_f32_32x32x16_f16(A0, pt[k], acc0, 0, 0, 0);
      acc1 = __builtin_amdgcn_mfma_f32_32x32x16_f16(A1, pt[k], acc1, 0, 0, 0);
    }
    __builtin_amdgcn_s_setprio(0);
  }
  #pragma unroll
  for (int t = 0; t < 4; t++) {
    int c0 = 8 * t + 4 * g;
    int kb = c0 >> 4, sub = c0 & 15;
    ushort4v s0, s1;
    #pragma unroll
    for (int u = 0; u < 4; u++) {
      s0[u] = f2h(acc0[4 * t + u] + cbias[c0 + u]);
      s1[u] = f2h(acc1[4 * t + u] + cbias[c0 + u + 32]);
    }
    *(ushort4v*)(ipad + clb(b, h, kb, w, 128) + sub) = s0;
    *(ushort4v*)(ipad + clb(b, h, kb + 2, w, 128) + sub) = s1;
  }
}

// ---------------- stage 5: fr 1x1 + residual (direct epilogue add) ----------
__global__ __launch_bounds__(256, 4) void k_fr_mfma(
    const unsigned short* __restrict__ ipad,
    const unsigned short* __restrict__ apfr,
    const float* __restrict__ bias,
    unsigned short* __restrict__ opad)
{
  int b, h; swz_bh(b, h);
  const int tid = threadIdx.x, wv = tid >> 6, l = tid & 63;
  const int ln31 = l & 31, g = l >> 5;
  const int px = wv * 32 + ln31;
  v16f acc0, acc1;
  #pragma unroll
  for (int r = 0; r < 16; r++) { acc0[r] = 0.f; acc1[r] = 0.f; }
  const unsigned short* apl = apfr + l * 8;
  #pragma unroll
  for (int kb = 0; kb < 4; kb++) {
    v8h Bf = *(const v8h*)(ipad + clb(b, h, kb, px, 128) + g * 8);
    v8h A0 = *(const v8h*)(apl + (kb * 2) * 512);
    v8h A1 = *(const v8h*)(apl + (kb * 2 + 1) * 512);
    acc0 = __builtin_amdgcn_mfma_f32_32x32x16_f16(A0, Bf, acc0, 0, 0, 0);
    acc1 = __builtin_amdgcn_mfma_f32_32x32x16_f16(A1, Bf, acc1, 0, 0, 0);
  }
  #pragma unroll
  for (int t = 0; t < 4; t++) {
    int c0 = 8 * t + 4 * g;
    int kb = c0 >> 4, sub = c0 & 15;
    // residual values live at exactly the epilogue addresses
    ushort4v r0 = *(const ushort4v*)(ipad + clb(b, h, kb, px, 128) + sub);
    ushort4v r1 = *(const ushort4v*)(ipad + clb(b, h, kb + 2, px, 128) + sub);
    ushort4v s0, s1;
    #pragma unroll
    for (int u = 0; u < 4; u++) {
      s0[u] = f2h(acc0[4 * t + u] + bias[c0 + u] + h2f(r0[u]));
      s1[u] = f2h(acc1[4 * t + u] + bias[c0 + u + 32] + h2f(r1[u]));
    }
    *(ushort4v*)(opad + clb(b, h + 1, kb, px + 1, PE) + sub) = s0;
    *(ushort4v*)(opad + clb(b, h + 1, kb + 2, px + 1, PE) + sub) = s1;
  }
}

// ---------------- stage 6: ensemble conv3x3, 2 rows/block, LDS weights ------
__global__ __launch_bounds__(256) void k_ens_mfma(
    const unsigned short* __restrict__ opad,
    const unsigned short* __restrict__ apens,
    const float* __restrict__ esc, const float* __restrict__ ebi,
    float* __restrict__ out)
{
  __shared__ __align__(16) unsigned short Abuf[36864];  // 72 KB: 9 taps
  const int tid = threadIdx.x;
  {
    const ushort8v* src = (const ushort8v*)apens;
    ushort8v* dst = (ushort8v*)Abuf;
    #pragma unroll
    for (int it = 0; it < 18; it++)
      dst[tid + it * 256] = src[tid + it * 256];
  }
  __syncthreads();

  const int bid = blockIdx.x;
  const int b = bid & 7, h0 = (bid >> 3) * 2;
  const int wv = tid >> 6, l = tid & 63;
  const int ln31 = l & 31, g = l >> 5;

  v16f a00, a01, a10, a11;
  #pragma unroll
  for (int r = 0; r < 16; r++) { a00[r] = 0.f; a01[r] = 0.f; a10[r] = 0.f; a11[r] = 0.f; }

  const unsigned short* abl = Abuf + l * 8;

  #pragma unroll
  for (int ky = 0; ky < 3; ky++) {
    #pragma unroll
    for (int kx = 0; kx < 3; kx++) {
      const int tap = ky * 3 + kx;
      const int r0 = h0 + ky;              // (h0+1) + (ky-1)
      const int col = wv * 32 + ln31 + kx; // (+1) + (kx-1)
      const unsigned short* ap = abl + tap * 4096;
      #pragma unroll
      for (int kb = 0; kb < 4; kb++) {
        v8h B0 = *(const v8h*)(opad + clb(b, r0, kb, col, PE) + g * 8);
        v8h B1 = *(const v8h*)(opad + clb(b, r0 + 1, kb, col, PE) + g * 8);
        v8h A0 = *(const v8h*)(ap + kb * 1024);
        v8h A1 = *(const v8h*)(ap + kb * 1024 + 512);
        a00 = __builtin_amdgcn_mfma_f32_32x32x16_f16(A0, B0, a00, 0, 0, 0);
        a01 = __builtin_amdgcn_mfma_f32_32x32x16_f16(A1, B0, a01, 0, 0, 0);
        a10 = __builtin_amdgcn_mfma_f32_32x32x16_f16(A0, B1, a10, 0, 0, 0);
        a11 = __builtin_amdgcn_mfma_f32_32x32x16_f16(A1, B1, a11, 0, 0, 0);
      }
    }
  }
  float* sp0 = out + ((size_t)b * Cn) * Pn + h0 * Wn + wv * 32 + ln31;
  float* sp1 = sp0 + Wn;
  #pragma unroll
  for (int r = 0; r < 16; r++) {
    int o0 = (r & 3) + 8 * (r >> 2) + 4 * g;
    float e0 = esc[o0], e1 = esc[o0 + 32];
    float i0 = ebi[o0], i1 = ebi[o0 + 32];
    sp0[(size_t)o0 * Pn] = fmaxf(a00[r] * e0 + i0, 0.f);
    sp0[(size_t)(o0 + 32) * Pn] = fmaxf(a01[r] * e1 + i1, 0.f);
    sp1[(size_t)o0 * Pn] = fmaxf(a10[r] * e0 + i0, 0.f);
    sp1[(size_t)(o0 + 32) * Pn] = fmaxf(a11[r] * e1 + i1, 0.f);
  }
}

extern "C" void kernel_launch(void* const* d_in, const int* in_sizes, int n_in,
                              void* d_out, int out_size, void* d_ws, size_t ws_size,
                              hipStream_t stream)
{
  const float* x    = (const float*)d_in[0];
  const float* w1   = (const float*)d_in[1];
  const float* b1   = (const float*)d_in[2];
  const float* w5   = (const float*)d_in[3];
  const float* w7   = (const float*)d_in[4];
  const float* w9   = (const float*)d_in[5];
  const float* w11  = (const float*)d_in[6];
  const float* dww  = (const float*)d_in[7];
  const float* dwb  = (const float*)d_in[8];
  const float* pww  = (const float*)d_in[9];
  const float* pwb  = (const float*)d_in[10];
  const float* gww  = (const float*)d_in[11];
  const float* gwb  = (const float*)d_in[12];
  const float* gbg  = (const float*)d_in[13];
  const float* gbb  = (const float*)d_in[14];
  const float* gbm  = (const float*)d_in[15];
  const float* gbv  = (const float*)d_in[16];
  const float* cw   = (const float*)d_in[17];
  const float* cb   = (const float*)d_in[18];
  const float* frw  = (const float*)d_in[19];
  const float* frb  = (const float*)d_in[20];
  const float* ensw = (const float*)d_in[21];
  const float* ensb = (const float*)d_in[22];
  const float* bng  = (const float*)d_in[23];
  const float* bnb  = (const float*)d_in[24];
  const float* bnm  = (const float*)d_in[25];
  const float* bnv  = (const float*)d_in[26];

  // ws: ypad (pad-11) region, overlaid later by y2pad then opad (pad-1)
  unsigned short* wsu   = (unsigned short*)d_ws;
  unsigned short* ypad  = wsu;
  unsigned short* y2pad = wsu;
  unsigned short* opad  = wsu;
  unsigned short* apack = wsu + YPAD_ELEMS;         // 147456
  unsigned short* apinv = apack + 147456;           // 36864
  unsigned short* apens = apinv + 36864;            // 36864
  unsigned short* appw1 = apens + 36864;            // 4096
  unsigned short* appw  = appw1 + 4096;             // 4096
  unsigned short* apfr  = appw + 4096;              // 4096
  unsigned short* gwpk  = apfr + 4096;              // 5184
  unsigned short* apk   = gwpk + 5184;              // 576
  unsigned short* bpk   = apk + 576;                // 576
  float* esc = (float*)(bpk + 576);                 // 64
  float* ebi = esc + 64;                            // 64

  // d_out: spad (fp16 blocked-CL pad-1) -> ipad (blocked-CL) -> planar fp32
  unsigned short* spad = (unsigned short*)d_out;
  unsigned short* ipad = (unsigned short*)d_out;
  float* D = (float*)d_out;

  // prep also zeroes ypad borders (pad 11) and spad borders (pad 1)
  k_prep<<<1145, 256, 0, stream>>>(w1, w5, w7, w9, w11, pww, frw, cw,
                                   gww, gwb, gbg, gbb, gbm, gbv, ensw, ensb,
                                   bng, bnb, bnm, bnv,
                                   apack, apinv, apens, appw1, appw, apfr,
                                   gwpk, apk, bpk, esc, ebi,
                                   ypad, spad);

  // 1) ypad = conv1x1(relu(x))           x (planar f32) -> ypad (blocked CL)
  k_pw1x<<<1024, 256, 0, stream>>>(x, appw1, b1, ypad);
  // 2) spad = sum_d dilconv_d(y)         ypad -> spad (d_out, pad-1)
  k_cdcm_mfma<<<256, 1024, 0, stream>>>(ypad, apack, spad);
  // 3) y2pad = PW(DW(spad))              spad -> y2pad (ws, pad-1)
  //    (blocks h=0/1 also zero y2pad borders; ypad is dead by now)
  k_dwpw_mfma<<<1024, 256, 0, stream>>>(spad, dww, dwb, appw, pwb, y2pad);
  // 4) ipad = involution(y2pad)          y2pad -> ipad (d_out)
  k_invol_mfma<<<1024, 256, 0, stream>>>(y2pad, gwpk, apk, bpk, apinv, cb, ipad);
  // 5) opad = fr(ipad) + ipad            ipad -> opad (ws, pad-1)
  k_fr_mfma<<<1024, 256, 0, stream>>>(ipad, apfr, frb, opad);
  // 6) out = relu(BN(ens3x3(opad)))      opad -> D (planar fp32)
  k_ens_mfma<<<512, 256, 0, stream>>>(opad, apens, esc, ebi, D);
}